// Round 9
// baseline (255.562 us; speedup 1.0000x reference)
//
#include <hip/hip_runtime.h>
#include <hip/hip_fp16.h>
#include <stdint.h>

// HashEmbedder (Instant-NGP hash grid), MI355X gfx950.
// R12 -> R13. R12: 246.3us; mixed 75.4us @ 18M VMEM instr = 0.39 instr/cyc/CU
// (HALF R9's 0.79 rate) -> pure instruction-rate model wrong. Linear fit
// across rounds: cyc/pt-level ~= 1.05*gathers + 6.8. The 6.8-cyc constant
// (x-load + store + VALU + latency, paid once per level-PASS per point) now
// dominates. R13 amortizes it: (a) GROUP levels 3+4+5 in one pass (tables
// 3.63MB fit one L2 together; x loaded once for 3 levels); L6, L7 solo.
// (b) fp16 ws (x8192-scaled): stores 1 uint4/4pts/level, transpose 6 VMEM/pt.
// (c) table-builds fused to 1 launch; LDS kernels vectorized 4pt/thread.
// Predicted: grouped ~50-60us, transpose ~15us, total ~210-220us.

#define TABLE_SIZE (1u << 19)
#define TMASK (TABLE_SIZE - 1u)
#define P2 2654435761u
#define P3 805459861u

#define FSCALE 8192.0f
#define FINV   1.220703125e-4f   // 1/8192, exact pow2

// scratch layout inside `out` (64MB, dead after aos pass):
//   [0, 254KB):        f32 coarse dense tables (LDS path, levels 0..2)
//   [256KB, ~8.2MB):   fp16 quad tables, levels 3..6 (uint4, SCALED x8192)
//   [16MB, ~20.2MB):   fp16 pair table, level 7 (uint2, SCALED x8192)
#define QUAD_BYTES_OFF 262144
#define PAIR_BYTES_OFF 16777216

// quad offsets (uint4 units): L3:0 L4:33792 L5:99392 L6:226892 end 493132
#define OFF_Q3 0
#define OFF_Q4 33792
#define OFF_Q5 99392
#define OFF_Q6 226892

__device__ __forceinline__ uint32_t pack_s(float a, float b) {   // scale+pack
    __half2 h = __floats2half2_rn(a * FSCALE, b * FSCALE);
    return *(uint32_t*)&h;
}
__device__ __forceinline__ uint32_t pack_r(float a, float b) {   // raw pack
    __half2 h = __floats2half2_rn(a, b);
    return *(uint32_t*)&h;
}
__device__ __forceinline__ float2 h2f(uint32_t u) {
    __half2 h = *(__half2*)&u;
    return __half22float2(h);
}
__device__ __forceinline__ uint32_t getc(const uint4 v, int k) {
    return k == 0 ? v.x : k == 1 ? v.y : k == 2 ? v.z : v.w;
}

// ---------------- kernel 0: build all derived tables (one launch) ---------
// role (blockIdx.y): 0..3 -> quad level 3+role; 4 -> pair7; 5 -> coarse f32
__global__ __launch_bounds__(256) void build_tables_kernel(
    const float* __restrict__ tables, float2* __restrict__ dense,
    uint4* __restrict__ quads, uint2* __restrict__ pairs)
{
    const int role = (int)blockIdx.y;
    const int e = (int)blockIdx.x * 256 + (int)threadIdx.x;

    if (role < 4) {
        int DK, offq, l = 3 + role;
        switch (role) {
            case 0: DK = 32; offq = OFF_Q3; break;
            case 1: DK = 40; offq = OFF_Q4; break;
            case 2: DK = 50; offq = OFF_Q5; break;
            default:DK = 64; offq = OFF_Q6; break;
        }
        const int E = (DK + 1) * DK * DK;
        if (e >= E) return;
        const int d2 = DK * DK;
        const int i = e / d2;
        const int rem = e - i * d2;
        const int j = rem / DK;
        const int k = rem - j * DK;
        const float2* __restrict__ tab = (const float2*)tables + (size_t)l * (size_t)TABLE_SIZE;
        const uint32_t hx  = (uint32_t)i;
        const uint32_t hy0 = (uint32_t)j * P2, hy1 = hy0 + P2;
        const uint32_t hz0 = (uint32_t)k * P3, hz1 = hz0 + P3;
        const float2 v00 = tab[(hx ^ hy0 ^ hz0) & TMASK];
        const float2 v01 = tab[(hx ^ hy0 ^ hz1) & TMASK];
        const float2 v10 = tab[(hx ^ hy1 ^ hz0) & TMASK];
        const float2 v11 = tab[(hx ^ hy1 ^ hz1) & TMASK];
        uint4 u;
        u.x = pack_s(v00.x, v00.y);
        u.y = pack_s(v01.x, v01.y);
        u.z = pack_s(v10.x, v10.y);
        u.w = pack_s(v11.x, v11.y);
        quads[offq + e] = u;
    } else if (role == 4) {
        const int E = 81 * 81 * 80;     // 524,880
        if (e >= E) return;
        const int i = e / 6480;         // 81*80
        const int rem = e - i * 6480;
        const int j = rem / 80;
        const int k = rem - j * 80;
        const float2* __restrict__ tab = (const float2*)tables + (size_t)7 * (size_t)TABLE_SIZE;
        const uint32_t hb = (uint32_t)i ^ ((uint32_t)j * P2);
        const float2 a = tab[(hb ^ ((uint32_t)k * P3)) & TMASK];
        const float2 b = tab[(hb ^ ((uint32_t)(k + 1) * P3)) & TMASK];
        uint2 u;
        u.x = pack_s(a.x, a.y);
        u.y = pack_s(b.x, b.y);
        pairs[e] = u;
    } else {
        if (e >= 31750) return;
        int lv, DIM, off;
        if (e < 4913)       { lv = 0; DIM = 17; off = 0; }
        else if (e < 14174) { lv = 1; DIM = 21; off = 4913; }
        else                { lv = 2; DIM = 26; off = 14174; }
        const int le = e - off;
        const int d2 = DIM * DIM;
        const int i = le / d2;
        const int rem = le - i * d2;
        const int j = rem / DIM;
        const int k = rem - j * DIM;
        const uint32_t h = ((uint32_t)i ^ ((uint32_t)j * P2) ^ ((uint32_t)k * P3)) & TMASK;
        const float2* __restrict__ tab = (const float2*)tables + (size_t)lv * (size_t)TABLE_SIZE;
        dense[e] = tab[h];
    }
}

// ---------------- per-level gather state (4 points) -----------------------
struct PQ {                                // quad level
    uint4 qa[4], qb[4];
    float wx[4], wy[4], wz[4];
};
struct PP {                                // pair level 7
    uint2 d00[4], d01[4], d10[4], d11[4];
    float wx[4], wy[4], wz[4];
};

template<int DK>
__device__ __forceinline__ void q_issue(const uint4* __restrict__ tab,
        const float px[4], const float py[4], const float pz[4], PQ& s)
{
    const float R = (float)DK, g = 1.0f / R;
    const int d2 = DK * DK;
#pragma unroll
    for (int k = 0; k < 4; ++k) {
        const float cx = fminf(fmaxf(px[k], 0.0f), 1.0f);
        const float cy = fminf(fmaxf(py[k], 0.0f), 1.0f);
        const float cz = fminf(fmaxf(pz[k], 0.0f), 1.0f);
        const int bx = min((int)floorf(cx * R), DK - 1);
        const int by = min((int)floorf(cy * R), DK - 1);
        const int bz = min((int)floorf(cz * R), DK - 1);
        s.wx[k] = (px[k] - (float)bx * g) * R;
        s.wy[k] = (py[k] - (float)by * g) * R;
        s.wz[k] = (pz[k] - (float)bz * g) * R;
        const int ia = (bx * DK + by) * DK + bz;
        s.qa[k] = tab[ia];
        s.qb[k] = tab[ia + d2];
    }
}

__device__ __forceinline__ uint4 q_finish(const PQ& s)
{
    uint32_t r[4];
#pragma unroll
    for (int k = 0; k < 4; ++k) {
        const float wx = s.wx[k], wy = s.wy[k], wz = s.wz[k];
        const float omx = 1.0f - wx, omy = 1.0f - wy, omz = 1.0f - wz;
        const float2 a00 = h2f(s.qa[k].x), a01 = h2f(s.qa[k].y);
        const float2 a10 = h2f(s.qa[k].z), a11 = h2f(s.qa[k].w);
        const float2 b00 = h2f(s.qb[k].x), b01 = h2f(s.qb[k].y);
        const float2 b10 = h2f(s.qb[k].z), b11 = h2f(s.qb[k].w);
        const float m00a = a00.x*omx + b00.x*wx, m00b = a00.y*omx + b00.y*wx;
        const float m01a = a01.x*omx + b01.x*wx, m01b = a01.y*omx + b01.y*wx;
        const float m10a = a10.x*omx + b10.x*wx, m10b = a10.y*omx + b10.y*wx;
        const float m11a = a11.x*omx + b11.x*wx, m11b = a11.y*omx + b11.y*wx;
        const float c0a = m00a*omz + m01a*wz, c0b = m00b*omz + m01b*wz;
        const float c1a = m10a*omz + m11a*wz, c1b = m10b*omz + m11b*wz;
        r[k] = pack_r(c0a*omy + c1a*wy, c0b*omy + c1b*wy);   // still x8192
    }
    return make_uint4(r[0], r[1], r[2], r[3]);
}

__device__ __forceinline__ void p_issue(const uint2* __restrict__ pairs,
        const float px[4], const float py[4], const float pz[4], PP& s)
{
    const float R = 80.f, g = 1.0f / R;
#pragma unroll
    for (int k = 0; k < 4; ++k) {
        const float cx = fminf(fmaxf(px[k], 0.0f), 1.0f);
        const float cy = fminf(fmaxf(py[k], 0.0f), 1.0f);
        const float cz = fminf(fmaxf(pz[k], 0.0f), 1.0f);
        const int bx = min((int)floorf(cx * R), 79);
        const int by = min((int)floorf(cy * R), 79);
        const int bz = min((int)floorf(cz * R), 79);
        s.wx[k] = (px[k] - (float)bx * g) * R;
        s.wy[k] = (py[k] - (float)by * g) * R;
        s.wz[k] = (pz[k] - (float)bz * g) * R;
        const int ix = (bx * 81 + by) * 80 + bz;
        s.d00[k] = pairs[ix];
        s.d01[k] = pairs[ix + 80];
        s.d10[k] = pairs[ix + 6480];
        s.d11[k] = pairs[ix + 6560];
    }
}

__device__ __forceinline__ uint4 p_finish(const PP& s)
{
    uint32_t r[4];
#pragma unroll
    for (int k = 0; k < 4; ++k) {
        const float wx = s.wx[k], wy = s.wy[k], wz = s.wz[k];
        const float omx = 1.0f - wx, omy = 1.0f - wy, omz = 1.0f - wz;
        const float2 a00 = h2f(s.d00[k].x), z00 = h2f(s.d00[k].y);
        const float2 a01 = h2f(s.d01[k].x), z01 = h2f(s.d01[k].y);
        const float2 a10 = h2f(s.d10[k].x), z10 = h2f(s.d10[k].y);
        const float2 a11 = h2f(s.d11[k].x), z11 = h2f(s.d11[k].y);
        const float c00a = a00.x*omz + z00.x*wz, c00b = a00.y*omz + z00.y*wz;
        const float c01a = a01.x*omz + z01.x*wz, c01b = a01.y*omz + z01.y*wz;
        const float c10a = a10.x*omz + z10.x*wz, c10b = a10.y*omz + z10.y*wz;
        const float c11a = a11.x*omz + z11.x*wz, c11b = a11.y*omz + z11.y*wz;
        const float e0a = c00a*omy + c01a*wy, e0b = c00b*omy + c01b*wy;
        const float e1a = c10a*omy + c11a*wy, e1b = c10b*omy + c11b*wy;
        r[k] = pack_r(e0a*omx + e1a*wx, e0b*omx + e1b*wx);
    }
    return make_uint4(r[0], r[1], r[2], r[3]);
}

__device__ __forceinline__ void store4(uint32_t* __restrict__ wsh,
        size_t lofs, int p0, int n, uint4 r)
{
    if (p0 + 4 <= n) {
        *(uint4*)(wsh + lofs + p0) = r;
    } else {
#pragma unroll
        for (int k = 0; k < 4; ++k)
            if (p0 + k < n) wsh[lofs + p0 + k] = getc(r, k);
    }
}

// ---------------- kernel 1: grouped gather embed --------------------------
// group 0: levels 3+4+5 (tables 3.63MB, co-resident in L2; x loaded ONCE for
// 3 levels). group 1: level 6 quad. group 2: level 7 pairs. Group-major
// block order -> whole chip works one table set at a time.
__global__ __launch_bounds__(256) void embed_grouped_kernel(
    const float* __restrict__ x, const uint4* __restrict__ quads,
    const uint2* __restrict__ pairs, uint32_t* __restrict__ wsh,
    int n, int bpl)
{
    const int bid = (int)blockIdx.x;
    const int grp = bid / bpl;
    const int pb = bid - grp * bpl;
    const int p0 = pb * 1024 + 4 * (int)threadIdx.x;
    if (p0 >= n) return;

    float px[4], py[4], pz[4];
    if (p0 + 4 <= n) {
        const float4* __restrict__ xv = (const float4*)(x + (size_t)3 * p0);
        const float4 f0 = xv[0], f1 = xv[1], f2 = xv[2];
        px[0] = f0.x; py[0] = f0.y; pz[0] = f0.z;
        px[1] = f0.w; py[1] = f1.x; pz[1] = f1.y;
        px[2] = f1.z; py[2] = f1.w; pz[2] = f2.x;
        px[3] = f2.y; py[3] = f2.z; pz[3] = f2.w;
    } else {
#pragma unroll
        for (int k = 0; k < 4; ++k) {
            const int i = min(p0 + k, n - 1);
            px[k] = x[3*i]; py[k] = x[3*i+1]; pz[k] = x[3*i+2];
        }
    }

    if (grp == 0) {
        PQ s3, s4, s5;
        q_issue<32>(quads + OFF_Q3, px, py, pz, s3);
        q_issue<40>(quads + OFF_Q4, px, py, pz, s4);
        store4(wsh, (size_t)3 * n, p0, n, q_finish(s3));
        q_issue<50>(quads + OFF_Q5, px, py, pz, s5);
        store4(wsh, (size_t)4 * n, p0, n, q_finish(s4));
        store4(wsh, (size_t)5 * n, p0, n, q_finish(s5));
    } else if (grp == 1) {
        PQ s6;
        q_issue<64>(quads + OFF_Q6, px, py, pz, s6);
        store4(wsh, (size_t)6 * n, p0, n, q_finish(s6));
    } else {
        PP s7;
        p_issue(pairs, px, py, pz, s7);
        store4(wsh, (size_t)7 * n, p0, n, p_finish(s7));
    }
}

// ---------------- kernel L: LDS-table embed (levels 0..2, f32 exact) ------
// 1024 thr x 4 pts/thread = 4096 pts/block; fp16 (x8192) stores to wsh.
__global__ __launch_bounds__(1024) void embed_lds_kernel(
    const float* __restrict__ x, const float2* __restrict__ dense,
    uint32_t* __restrict__ wsh, int n, int lv, int DIM, int E, int doff)
{
    extern __shared__ float2 lds[];
    for (int e = (int)threadIdx.x; e < E; e += 1024) lds[e] = dense[doff + e];
    __syncthreads();

    const int p0 = ((int)blockIdx.x * 1024 + (int)threadIdx.x) * 4;
    if (p0 >= n) return;

    const float R = (lv == 0) ? 16.f : (lv == 1) ? 20.f : 25.f;
    const float g = 1.0f / R;
    const int D2 = DIM * DIM;
    const int bmax = DIM - 2;

    float px[4], py[4], pz[4];
    if (p0 + 4 <= n) {
        const float4* __restrict__ xv = (const float4*)(x + (size_t)3 * p0);
        const float4 f0 = xv[0], f1 = xv[1], f2 = xv[2];
        px[0] = f0.x; py[0] = f0.y; pz[0] = f0.z;
        px[1] = f0.w; py[1] = f1.x; pz[1] = f1.y;
        px[2] = f1.z; py[2] = f1.w; pz[2] = f2.x;
        px[3] = f2.y; py[3] = f2.z; pz[3] = f2.w;
    } else {
#pragma unroll
        for (int k = 0; k < 4; ++k) {
            const int i = min(p0 + k, n - 1);
            px[k] = x[3*i]; py[k] = x[3*i+1]; pz[k] = x[3*i+2];
        }
    }

    uint32_t r[4];
#pragma unroll
    for (int k = 0; k < 4; ++k) {
        const float cx = fminf(fmaxf(px[k], 0.0f), 1.0f);
        const float cy = fminf(fmaxf(py[k], 0.0f), 1.0f);
        const float cz = fminf(fmaxf(pz[k], 0.0f), 1.0f);
        const int bx = min((int)floorf(cx * R), bmax);
        const int by = min((int)floorf(cy * R), bmax);
        const int bz = min((int)floorf(cz * R), bmax);
        const float wx = (px[k] - (float)bx * g) * R;
        const float wy = (py[k] - (float)by * g) * R;
        const float wz = (pz[k] - (float)bz * g) * R;
        const int c = (bx * DIM + by) * DIM + bz;
        const float2 e000 = lds[c];
        const float2 e001 = lds[c + 1];
        const float2 e010 = lds[c + DIM];
        const float2 e011 = lds[c + DIM + 1];
        const float2 e100 = lds[c + D2];
        const float2 e101 = lds[c + D2 + 1];
        const float2 e110 = lds[c + D2 + DIM];
        const float2 e111 = lds[c + D2 + DIM + 1];
        const float omx = 1.0f - wx, omy = 1.0f - wy, omz = 1.0f - wz;
        const float c00a = e000.x*omx + e100.x*wx, c00b = e000.y*omx + e100.y*wx;
        const float c01a = e001.x*omx + e101.x*wx, c01b = e001.y*omx + e101.y*wx;
        const float c10a = e010.x*omx + e110.x*wx, c10b = e010.y*omx + e110.y*wx;
        const float c11a = e011.x*omx + e111.x*wx, c11b = e011.y*omx + e111.y*wx;
        const float c0a = c00a*omy + c10a*wy, c0b = c00b*omy + c10b*wy;
        const float c1a = c01a*omy + c11a*wy, c1b = c01b*omy + c11b*wy;
        r[k] = pack_s(c0a*omz + c1a*wz, c0b*omz + c1b*wz);
    }
    store4(wsh, (size_t)lv * n, p0, n, make_uint4(r[0], r[1], r[2], r[3]));
}

// ---------------- kernel 2: fp16 SoA -> f32 AoS ---------------------------
__global__ __launch_bounds__(256) void aos_kernel(
    const uint32_t* __restrict__ wsh, float* __restrict__ out, int n)
{
    const int p0 = ((int)blockIdx.x * 256 + (int)threadIdx.x) * 4;
    if (p0 >= n) return;

    if (p0 + 4 <= n) {
        const uint4 v0 = *(const uint4*)(wsh + 0 * (size_t)n + p0);
        const uint4 v1 = *(const uint4*)(wsh + 1 * (size_t)n + p0);
        const uint4 v2 = *(const uint4*)(wsh + 2 * (size_t)n + p0);
        const uint4 v3 = *(const uint4*)(wsh + 3 * (size_t)n + p0);
        const uint4 v4 = *(const uint4*)(wsh + 4 * (size_t)n + p0);
        const uint4 v5 = *(const uint4*)(wsh + 5 * (size_t)n + p0);
        const uint4 v6 = *(const uint4*)(wsh + 6 * (size_t)n + p0);
        const uint4 v7 = *(const uint4*)(wsh + 7 * (size_t)n + p0);
#pragma unroll
        for (int k = 0; k < 4; ++k) {
            const float2 f0 = h2f(getc(v0, k)), f1 = h2f(getc(v1, k));
            const float2 f2 = h2f(getc(v2, k)), f3 = h2f(getc(v3, k));
            const float2 f4 = h2f(getc(v4, k)), f5 = h2f(getc(v5, k));
            const float2 f6 = h2f(getc(v6, k)), f7 = h2f(getc(v7, k));
            float4* __restrict__ op = (float4*)(out + (size_t)(p0 + k) * 16);
            op[0] = make_float4(f0.x*FINV, f0.y*FINV, f1.x*FINV, f1.y*FINV);
            op[1] = make_float4(f2.x*FINV, f2.y*FINV, f3.x*FINV, f3.y*FINV);
            op[2] = make_float4(f4.x*FINV, f4.y*FINV, f5.x*FINV, f5.y*FINV);
            op[3] = make_float4(f6.x*FINV, f6.y*FINV, f7.x*FINV, f7.y*FINV);
        }
    } else {
        for (int k = 0; k < 4 && p0 + k < n; ++k) {
            const int i = p0 + k;
            float* __restrict__ op = out + (size_t)i * 16;
#pragma unroll
            for (int l = 0; l < 8; ++l) {
                const float2 f = h2f(wsh[(size_t)l * n + i]);
                op[2*l + 0] = f.x * FINV;
                op[2*l + 1] = f.y * FINV;
            }
        }
    }
}

// ---------------- fallback: monolithic, f32 exact -------------------------
__global__ __launch_bounds__(256) void hash_embed_mono_kernel(
    const float* __restrict__ x, const float* __restrict__ tables,
    float* __restrict__ out, int n)
{
    const int i = blockIdx.x * 256 + threadIdx.x;
    if (i >= n) return;
    const float px = x[3*i+0], py = x[3*i+1], pz = x[3*i+2];
    const float cx = fminf(fmaxf(px, 0.0f), 1.0f);
    const float cy = fminf(fmaxf(py, 0.0f), 1.0f);
    const float cz = fminf(fmaxf(pz, 0.0f), 1.0f);
    const float resf[8] = {16.f,20.f,25.f,32.f,40.f,50.f,64.f,80.f};
    float o[16];
#pragma unroll
    for (int l = 0; l < 8; ++l) {
        const float R = resf[l], g = 1.0f / R;
        const int bx = (int)floorf(cx*R), by = (int)floorf(cy*R), bz = (int)floorf(cz*R);
        const float wx = (px - bx*g)*R, wy = (py - by*g)*R, wz = (pz - bz*g)*R;
        const uint32_t hx0 = (uint32_t)bx, hx1 = hx0+1u;
        const uint32_t hy0 = (uint32_t)by*P2, hy1 = hy0+P2;
        const uint32_t hz0 = (uint32_t)bz*P3, hz1 = hz0+P3;
        const float2* tab = (const float2*)(tables) + (size_t)l*(size_t)TABLE_SIZE;
        const float2 e000 = tab[(hx0^hy0^hz0)&TMASK], e001 = tab[(hx0^hy0^hz1)&TMASK];
        const float2 e010 = tab[(hx0^hy1^hz0)&TMASK], e011 = tab[(hx0^hy1^hz1)&TMASK];
        const float2 e100 = tab[(hx1^hy0^hz0)&TMASK], e101 = tab[(hx1^hy0^hz1)&TMASK];
        const float2 e110 = tab[(hx1^hy1^hz0)&TMASK], e111 = tab[(hx1^hy1^hz1)&TMASK];
        const float omx = 1.f-wx, omy = 1.f-wy, omz = 1.f-wz;
        const float c00a = e000.x*omx + e100.x*wx, c00b = e000.y*omx + e100.y*wx;
        const float c01a = e001.x*omx + e101.x*wx, c01b = e001.y*omx + e101.y*wx;
        const float c10a = e010.x*omx + e110.x*wx, c10b = e010.y*omx + e110.y*wx;
        const float c11a = e011.x*omx + e111.x*wx, c11b = e011.y*omx + e111.y*wx;
        const float c0a = c00a*omy + c10a*wy, c0b = c00b*omy + c10b*wy;
        const float c1a = c01a*omy + c11a*wy, c1b = c01b*omy + c11b*wy;
        o[2*l+0] = c0a*omz + c1a*wz;
        o[2*l+1] = c0b*omz + c1b*wz;
    }
    float4* op = (float4*)(out + (size_t)i * 16);
    op[0] = make_float4(o[0],o[1],o[2],o[3]);
    op[1] = make_float4(o[4],o[5],o[6],o[7]);
    op[2] = make_float4(o[8],o[9],o[10],o[11]);
    op[3] = make_float4(o[12],o[13],o[14],o[15]);
}

extern "C" void kernel_launch(void* const* d_in, const int* in_sizes, int n_in,
                              void* d_out, int out_size, void* d_ws, size_t ws_size,
                              hipStream_t stream) {
    const float* x = (const float*)d_in[0];
    const float* tables = (const float*)d_in[1];
    float* out = (float*)d_out;
    const int n = in_sizes[0] / 3;  // 1048576 points

    // >64KB dynamic LDS needs opt-in; wsh needs 8*n*4B = 32MB.
    static int cap = -1;
    if (cap < 0) {
        cap = (hipFuncSetAttribute((const void*)embed_lds_kernel,
                  hipFuncAttributeMaxDynamicSharedMemorySize, 140608) == hipSuccess)
              ? 1 : 0;
    }
    const size_t ws_needed = (size_t)8 * (size_t)n * sizeof(uint32_t);  // 32 MB
    if (ws_size < ws_needed || cap == 0) {
        hash_embed_mono_kernel<<<(n + 255) / 256, 256, 0, stream>>>(x, tables, out, n);
        return;
    }

    uint32_t* wsh = (uint32_t*)d_ws;
    float2* dense = (float2*)out;
    uint4*  quads = (uint4*)((char*)out + QUAD_BYTES_OFF);
    uint2*  pairs = (uint2*)((char*)out + PAIR_BYTES_OFF);

    // k0: all derived tables, one launch (grid.y: 4 quad levels, pair7, coarse)
    build_tables_kernel<<<dim3(2051, 6), 256, 0, stream>>>(tables, dense, quads, pairs);

    // LDS-path levels 0..2 (f32-exact compute, fp16 store)
    static const int DIMt[3] = {17, 21, 26};
    static const int Et[3]   = {4913, 9261, 17576};
    static const int OFFt[3] = {0, 4913, 14174};
    const int lgrid = (n + 4095) / 4096;
    for (int lv = 0; lv < 3; ++lv) {
        embed_lds_kernel<<<lgrid, 1024, (size_t)Et[lv] * sizeof(float2), stream>>>(
            x, dense, wsh, n, lv, DIMt[lv], Et[lv], OFFt[lv]);
    }

    // grouped gather: group-major {3,4,5}, {6}, {7}
    const int bpl = (n + 1023) / 1024;
    embed_grouped_kernel<<<3 * bpl, 256, 0, stream>>>(x, quads, pairs, wsh, n, bpl);

    aos_kernel<<<(n + 1023) / 1024, 256, 0, stream>>>(wsh, out, n);
}

// Round 10
// 255.502 us; speedup vs baseline: 1.0002x; 1.0002x over previous
//
#include <hip/hip_runtime.h>
#include <hip/hip_fp16.h>
#include <stdint.h>

// HashEmbedder (Instant-NGP hash grid), MI355X gfx950.
// R13 -> R14. R13 post-mortem: grouping levels 3+4+5 in one pass collapsed
// occupancy (62%->26.7%, VGPR 32->68) -- the 6.8 cyc/pt-level "constant" is
// latency exposure that needs waves to hide, NOT an amortizable fixed cost.
// Grouping is a dead end. R14 reverts to R12's per-level gather structure
// (transient state, VGPR ~32, occ ~60%) and keeps R13's consolidation wins:
// fp16 ws (1 uint4 store /4pts/level), single fused build launch, fp16->f32
// aos kernel, vectorized LDS kernels. 6 dispatches.
// Predicted: embed ~70-75us @ occ ~60%, aos ~16us, total ~230-240us.

#define TABLE_SIZE (1u << 19)
#define TMASK (TABLE_SIZE - 1u)
#define P2 2654435761u
#define P3 805459861u

#define FSCALE 8192.0f
#define FINV   1.220703125e-4f   // 1/8192, exact pow2

// scratch layout inside `out` (64MB, dead after aos pass):
//   [0, 254KB):        f32 coarse dense tables (LDS path, levels 0..2)
//   [256KB, ~8.2MB):   fp16 quad tables, levels 3..6 (uint4, SCALED x8192)
//   [16MB, ~20.2MB):   fp16 pair table, level 7 (uint2, SCALED x8192)
#define QUAD_BYTES_OFF 262144
#define PAIR_BYTES_OFF 16777216

// quad offsets (uint4 units): L3:0 L4:33792 L5:99392 L6:226892 end 493132
#define OFF_Q3 0
#define OFF_Q4 33792
#define OFF_Q5 99392
#define OFF_Q6 226892

__device__ __forceinline__ void quad_geom(int l, float& R, int& DK, int& offq) {
    switch (l) {
        case 3: R=32.f; DK=32; offq=OFF_Q3; break;
        case 4: R=40.f; DK=40; offq=OFF_Q4; break;
        case 5: R=50.f; DK=50; offq=OFF_Q5; break;
        default:R=64.f; DK=64; offq=OFF_Q6; break;
    }
}

__device__ __forceinline__ uint32_t pack_s(float a, float b) {   // scale+pack
    __half2 h = __floats2half2_rn(a * FSCALE, b * FSCALE);
    return *(uint32_t*)&h;
}
__device__ __forceinline__ uint32_t pack_r(float a, float b) {   // raw pack
    __half2 h = __floats2half2_rn(a, b);
    return *(uint32_t*)&h;
}
__device__ __forceinline__ float2 h2f(uint32_t u) {
    __half2 h = *(__half2*)&u;
    return __half22float2(h);
}
__device__ __forceinline__ uint32_t getc(const uint4 v, int k) {
    return k == 0 ? v.x : k == 1 ? v.y : k == 2 ? v.z : v.w;
}

// ---------------- kernel 0: build all derived tables (one launch) ---------
// role (blockIdx.y): 0..3 -> quad level 3+role; 4 -> pair7; 5 -> coarse f32
__global__ __launch_bounds__(256) void build_tables_kernel(
    const float* __restrict__ tables, float2* __restrict__ dense,
    uint4* __restrict__ quads, uint2* __restrict__ pairs)
{
    const int role = (int)blockIdx.y;
    const int e = (int)blockIdx.x * 256 + (int)threadIdx.x;

    if (role < 4) {
        float Rf; int DK, offq;
        quad_geom(3 + role, Rf, DK, offq);
        const int l = 3 + role;
        const int E = (DK + 1) * DK * DK;
        if (e >= E) return;
        const int d2 = DK * DK;
        const int i = e / d2;
        const int rem = e - i * d2;
        const int j = rem / DK;
        const int k = rem - j * DK;
        const float2* __restrict__ tab = (const float2*)tables + (size_t)l * (size_t)TABLE_SIZE;
        const uint32_t hx  = (uint32_t)i;
        const uint32_t hy0 = (uint32_t)j * P2, hy1 = hy0 + P2;
        const uint32_t hz0 = (uint32_t)k * P3, hz1 = hz0 + P3;
        const float2 v00 = tab[(hx ^ hy0 ^ hz0) & TMASK];
        const float2 v01 = tab[(hx ^ hy0 ^ hz1) & TMASK];
        const float2 v10 = tab[(hx ^ hy1 ^ hz0) & TMASK];
        const float2 v11 = tab[(hx ^ hy1 ^ hz1) & TMASK];
        uint4 u;
        u.x = pack_s(v00.x, v00.y);
        u.y = pack_s(v01.x, v01.y);
        u.z = pack_s(v10.x, v10.y);
        u.w = pack_s(v11.x, v11.y);
        quads[offq + e] = u;
    } else if (role == 4) {
        const int E = 81 * 81 * 80;     // 524,880
        if (e >= E) return;
        const int i = e / 6480;         // 81*80
        const int rem = e - i * 6480;
        const int j = rem / 80;
        const int k = rem - j * 80;
        const float2* __restrict__ tab = (const float2*)tables + (size_t)7 * (size_t)TABLE_SIZE;
        const uint32_t hb = (uint32_t)i ^ ((uint32_t)j * P2);
        const float2 a = tab[(hb ^ ((uint32_t)k * P3)) & TMASK];
        const float2 b = tab[(hb ^ ((uint32_t)(k + 1) * P3)) & TMASK];
        uint2 u;
        u.x = pack_s(a.x, a.y);
        u.y = pack_s(b.x, b.y);
        pairs[e] = u;
    } else {
        if (e >= 31750) return;
        int lv, DIM, off;
        if (e < 4913)       { lv = 0; DIM = 17; off = 0; }
        else if (e < 14174) { lv = 1; DIM = 21; off = 4913; }
        else                { lv = 2; DIM = 26; off = 14174; }
        const int le = e - off;
        const int d2 = DIM * DIM;
        const int i = le / d2;
        const int rem = le - i * d2;
        const int j = rem / DIM;
        const int k = rem - j * DIM;
        const uint32_t h = ((uint32_t)i ^ ((uint32_t)j * P2) ^ ((uint32_t)k * P3)) & TMASK;
        const float2* __restrict__ tab = (const float2*)tables + (size_t)lv * (size_t)TABLE_SIZE;
        dense[e] = tab[h];
    }
}

// ---------------- single-point tail helpers (packed scaled output) --------
__device__ uint32_t embed_quad_one(int l, const uint4* __restrict__ quads,
                                   float px, float py, float pz) {
    float R; int DK, offq;
    quad_geom(l, R, DK, offq);
    const float g = 1.0f / R;
    const float cx = fminf(fmaxf(px, 0.0f), 1.0f);
    const float cy = fminf(fmaxf(py, 0.0f), 1.0f);
    const float cz = fminf(fmaxf(pz, 0.0f), 1.0f);
    const int bx = min((int)floorf(cx * R), DK - 1);
    const int by = min((int)floorf(cy * R), DK - 1);
    const int bz = min((int)floorf(cz * R), DK - 1);
    const float wx = (px - (float)bx * g) * R;
    const float wy = (py - (float)by * g) * R;
    const float wz = (pz - (float)bz * g) * R;
    const int d2 = DK * DK;
    const int idx = (bx * DK + by) * DK + bz;
    const uint4 qa = quads[offq + idx];
    const uint4 qb = quads[offq + idx + d2];
    const float omx = 1.0f - wx, omy = 1.0f - wy, omz = 1.0f - wz;
    const float2 a00 = h2f(qa.x), a01 = h2f(qa.y), a10 = h2f(qa.z), a11 = h2f(qa.w);
    const float2 b00 = h2f(qb.x), b01 = h2f(qb.y), b10 = h2f(qb.z), b11 = h2f(qb.w);
    const float m00a = a00.x*omx + b00.x*wx, m00b = a00.y*omx + b00.y*wx;
    const float m01a = a01.x*omx + b01.x*wx, m01b = a01.y*omx + b01.y*wx;
    const float m10a = a10.x*omx + b10.x*wx, m10b = a10.y*omx + b10.y*wx;
    const float m11a = a11.x*omx + b11.x*wx, m11b = a11.y*omx + b11.y*wx;
    const float c0a = m00a*omz + m01a*wz, c0b = m00b*omz + m01b*wz;
    const float c1a = m10a*omz + m11a*wz, c1b = m10b*omz + m11b*wz;
    return pack_r(c0a*omy + c1a*wy, c0b*omy + c1b*wy);
}
__device__ uint32_t embed_pair7_one(const uint2* __restrict__ pairs,
                                    float px, float py, float pz) {
    const float R = 80.f, g = 1.0f / R;
    const float cx = fminf(fmaxf(px, 0.0f), 1.0f);
    const float cy = fminf(fmaxf(py, 0.0f), 1.0f);
    const float cz = fminf(fmaxf(pz, 0.0f), 1.0f);
    const int bx = min((int)floorf(cx * R), 79);
    const int by = min((int)floorf(cy * R), 79);
    const int bz = min((int)floorf(cz * R), 79);
    const float wx = (px - (float)bx * g) * R;
    const float wy = (py - (float)by * g) * R;
    const float wz = (pz - (float)bz * g) * R;
    const int idx = (bx * 81 + by) * 80 + bz;
    const uint2 d00 = pairs[idx];
    const uint2 d01 = pairs[idx + 80];
    const uint2 d10 = pairs[idx + 6480];
    const uint2 d11 = pairs[idx + 6560];
    const float omx = 1.0f - wx, omy = 1.0f - wy, omz = 1.0f - wz;
    const float2 a00 = h2f(d00.x), z00 = h2f(d00.y);
    const float2 a01 = h2f(d01.x), z01 = h2f(d01.y);
    const float2 a10 = h2f(d10.x), z10 = h2f(d10.y);
    const float2 a11 = h2f(d11.x), z11 = h2f(d11.y);
    const float c00a = a00.x*omz + z00.x*wz, c00b = a00.y*omz + z00.y*wz;
    const float c01a = a01.x*omz + z01.x*wz, c01b = a01.y*omz + z01.y*wz;
    const float c10a = a10.x*omz + z10.x*wz, c10b = a10.y*omz + z10.y*wz;
    const float c11a = a11.x*omz + z11.x*wz, c11b = a11.y*omz + z11.y*wz;
    const float e0a = c00a*omy + c01a*wy, e0b = c00b*omy + c01b*wy;
    const float e1a = c10a*omy + c11a*wy, e1b = c10b*omy + c11b*wy;
    return pack_r(e0a*omx + e1a*wx, e0b*omx + e1b*wx);
}

// ---------------- kernel 1: per-level gather embed (levels 3..7) ----------
// One level per block range (level-major -> table L2-resident chip-wide).
// Thread -> 4 consecutive points; transient state only (VGPR-light, R12
// structure). Levels 3..6: 2 fp16-quad gathers/pt; level 7: 4 pair gathers.
// Output: 1 uint4 (4x packed scaled fp16 pairs) per thread per level.
__global__ __launch_bounds__(256, 4) void embed_levels_kernel(
    const float* __restrict__ x, const uint4* __restrict__ quads,
    const uint2* __restrict__ pairs, uint32_t* __restrict__ wsh,
    int n, int bpl)
{
    const int bid = (int)blockIdx.x;
    const int q = bid / bpl;
    const int l = 3 + q;
    const int pb = bid - q * bpl;
    const int p0 = pb * 1024 + 4 * (int)threadIdx.x;
    if (p0 >= n) return;

    uint32_t* __restrict__ wl = wsh + (size_t)l * (size_t)n;

    if (p0 + 4 > n) {           // rare tail
        for (int pp = 0; pp < 4; ++pp) {
            const int i = p0 + pp;
            if (i >= n) break;
            const float px = x[3*i], py = x[3*i+1], pz = x[3*i+2];
            wl[i] = (l < 7) ? embed_quad_one(l, quads, px, py, pz)
                            : embed_pair7_one(pairs, px, py, pz);
        }
        return;
    }

    // 3 vector loads cover 4 points
    const float4* __restrict__ xv = (const float4*)(x + (size_t)3 * p0);
    const float4 f0 = xv[0], f1 = xv[1], f2 = xv[2];
    const float px0 = f0.x, py0 = f0.y, pz0 = f0.z;
    const float px1 = f0.w, py1 = f1.x, pz1 = f1.y;
    const float px2 = f1.z, py2 = f1.w, pz2 = f2.x;
    const float px3 = f2.y, py3 = f2.z, pz3 = f2.w;

    uint32_t r0, r1, r2, r3;

    if (l < 7) {
        // ---------------- quad path ----------------
        float R; int DK, offq;
        quad_geom(l, R, DK, offq);
        const float g = 1.0f / R;
        const int bmax = DK - 1;
        const int d2 = DK * DK;
        const uint4* __restrict__ tab = quads + offq;

#define QPREP(k) \
        const float cx##k = fminf(fmaxf(px##k, 0.0f), 1.0f); \
        const float cy##k = fminf(fmaxf(py##k, 0.0f), 1.0f); \
        const float cz##k = fminf(fmaxf(pz##k, 0.0f), 1.0f); \
        const int bx##k = min((int)floorf(cx##k * R), bmax); \
        const int by##k = min((int)floorf(cy##k * R), bmax); \
        const int bz##k = min((int)floorf(cz##k * R), bmax); \
        const float wx##k = (px##k - (float)bx##k * g) * R; \
        const float wy##k = (py##k - (float)by##k * g) * R; \
        const float wz##k = (pz##k - (float)bz##k * g) * R; \
        const int ia##k = (bx##k * DK + by##k) * DK + bz##k; \
        const int ib##k = ia##k + d2;

        QPREP(0) QPREP(1) QPREP(2) QPREP(3)

#define QGATHER(k) \
        const uint4 qa##k = tab[ia##k]; \
        const uint4 qb##k = tab[ib##k];

        QGATHER(0) QGATHER(1) QGATHER(2) QGATHER(3)

#define QINTERP(k, dst) { \
        const float omx = 1.0f - wx##k, omy = 1.0f - wy##k, omz = 1.0f - wz##k; \
        const float2 a00 = h2f(qa##k.x), a01 = h2f(qa##k.y); \
        const float2 a10 = h2f(qa##k.z), a11 = h2f(qa##k.w); \
        const float2 b00 = h2f(qb##k.x), b01 = h2f(qb##k.y); \
        const float2 b10 = h2f(qb##k.z), b11 = h2f(qb##k.w); \
        const float m00a = a00.x*omx + b00.x*wx##k, m00b = a00.y*omx + b00.y*wx##k; \
        const float m01a = a01.x*omx + b01.x*wx##k, m01b = a01.y*omx + b01.y*wx##k; \
        const float m10a = a10.x*omx + b10.x*wx##k, m10b = a10.y*omx + b10.y*wx##k; \
        const float m11a = a11.x*omx + b11.x*wx##k, m11b = a11.y*omx + b11.y*wx##k; \
        const float c0a = m00a*omz + m01a*wz##k, c0b = m00b*omz + m01b*wz##k; \
        const float c1a = m10a*omz + m11a*wz##k, c1b = m10b*omz + m11b*wz##k; \
        dst = pack_r(c0a*omy + c1a*wy##k, c0b*omy + c1b*wy##k); }

        QINTERP(0, r0) QINTERP(1, r1) QINTERP(2, r2) QINTERP(3, r3)
    } else {
        // ---------------- pair path (level 7, R=80) ----------------
        const float R = 80.f, g = 1.0f / R;

#define SPREP(k) \
        const float cx##k = fminf(fmaxf(px##k, 0.0f), 1.0f); \
        const float cy##k = fminf(fmaxf(py##k, 0.0f), 1.0f); \
        const float cz##k = fminf(fmaxf(pz##k, 0.0f), 1.0f); \
        const int bx##k = min((int)floorf(cx##k * R), 79); \
        const int by##k = min((int)floorf(cy##k * R), 79); \
        const int bz##k = min((int)floorf(cz##k * R), 79); \
        const float wx##k = (px##k - (float)bx##k * g) * R; \
        const float wy##k = (py##k - (float)by##k * g) * R; \
        const float wz##k = (pz##k - (float)bz##k * g) * R; \
        const int ix##k = (bx##k * 81 + by##k) * 80 + bz##k;

        SPREP(0) SPREP(1) SPREP(2) SPREP(3)

#define SGATHER(k) \
        const uint2 d00##k = pairs[ix##k]; \
        const uint2 d01##k = pairs[ix##k + 80]; \
        const uint2 d10##k = pairs[ix##k + 6480]; \
        const uint2 d11##k = pairs[ix##k + 6560];

        SGATHER(0) SGATHER(1) SGATHER(2) SGATHER(3)

#define SINTERP(k, dst) { \
        const float omx = 1.0f - wx##k, omy = 1.0f - wy##k, omz = 1.0f - wz##k; \
        const float2 a00 = h2f(d00##k.x), z00 = h2f(d00##k.y); \
        const float2 a01 = h2f(d01##k.x), z01 = h2f(d01##k.y); \
        const float2 a10 = h2f(d10##k.x), z10 = h2f(d10##k.y); \
        const float2 a11 = h2f(d11##k.x), z11 = h2f(d11##k.y); \
        const float c00a = a00.x*omz + z00.x*wz##k, c00b = a00.y*omz + z00.y*wz##k; \
        const float c01a = a01.x*omz + z01.x*wz##k, c01b = a01.y*omz + z01.y*wz##k; \
        const float c10a = a10.x*omz + z10.x*wz##k, c10b = a10.y*omz + z10.y*wz##k; \
        const float c11a = a11.x*omz + z11.x*wz##k, c11b = a11.y*omz + z11.y*wz##k; \
        const float e0a = c00a*omy + c01a*wy##k, e0b = c00b*omy + c01b*wy##k; \
        const float e1a = c10a*omy + c11a*wy##k, e1b = c10b*omy + c11b*wy##k; \
        dst = pack_r(e0a*omx + e1a*wx##k, e0b*omx + e1b*wx##k); }

        SINTERP(0, r0) SINTERP(1, r1) SINTERP(2, r2) SINTERP(3, r3)
    }

    *(uint4*)(wl + p0) = make_uint4(r0, r1, r2, r3);
}

// ---------------- kernel L: LDS-table embed (levels 0..2, f32 exact) ------
// 1024 thr x 4 pts/thread = 4096 pts/block; fp16 (x8192) stores to wsh.
__global__ __launch_bounds__(1024) void embed_lds_kernel(
    const float* __restrict__ x, const float2* __restrict__ dense,
    uint32_t* __restrict__ wsh, int n, int lv, int DIM, int E, int doff)
{
    extern __shared__ float2 lds[];
    for (int e = (int)threadIdx.x; e < E; e += 1024) lds[e] = dense[doff + e];
    __syncthreads();

    const int p0 = ((int)blockIdx.x * 1024 + (int)threadIdx.x) * 4;
    if (p0 >= n) return;

    const float R = (lv == 0) ? 16.f : (lv == 1) ? 20.f : 25.f;
    const float g = 1.0f / R;
    const int D2 = DIM * DIM;
    const int bmax = DIM - 2;

    float px[4], py[4], pz[4];
    if (p0 + 4 <= n) {
        const float4* __restrict__ xv = (const float4*)(x + (size_t)3 * p0);
        const float4 f0 = xv[0], f1 = xv[1], f2 = xv[2];
        px[0] = f0.x; py[0] = f0.y; pz[0] = f0.z;
        px[1] = f0.w; py[1] = f1.x; pz[1] = f1.y;
        px[2] = f1.z; py[2] = f1.w; pz[2] = f2.x;
        px[3] = f2.y; py[3] = f2.z; pz[3] = f2.w;
    } else {
#pragma unroll
        for (int k = 0; k < 4; ++k) {
            const int i = min(p0 + k, n - 1);
            px[k] = x[3*i]; py[k] = x[3*i+1]; pz[k] = x[3*i+2];
        }
    }

    uint32_t r[4];
#pragma unroll
    for (int k = 0; k < 4; ++k) {
        const float cx = fminf(fmaxf(px[k], 0.0f), 1.0f);
        const float cy = fminf(fmaxf(py[k], 0.0f), 1.0f);
        const float cz = fminf(fmaxf(pz[k], 0.0f), 1.0f);
        const int bx = min((int)floorf(cx * R), bmax);
        const int by = min((int)floorf(cy * R), bmax);
        const int bz = min((int)floorf(cz * R), bmax);
        const float wx = (px[k] - (float)bx * g) * R;
        const float wy = (py[k] - (float)by * g) * R;
        const float wz = (pz[k] - (float)bz * g) * R;
        const int c = (bx * DIM + by) * DIM + bz;
        const float2 e000 = lds[c];
        const float2 e001 = lds[c + 1];
        const float2 e010 = lds[c + DIM];
        const float2 e011 = lds[c + DIM + 1];
        const float2 e100 = lds[c + D2];
        const float2 e101 = lds[c + D2 + 1];
        const float2 e110 = lds[c + D2 + DIM];
        const float2 e111 = lds[c + D2 + DIM + 1];
        const float omx = 1.0f - wx, omy = 1.0f - wy, omz = 1.0f - wz;
        const float c00a = e000.x*omx + e100.x*wx, c00b = e000.y*omx + e100.y*wx;
        const float c01a = e001.x*omx + e101.x*wx, c01b = e001.y*omx + e101.y*wx;
        const float c10a = e010.x*omx + e110.x*wx, c10b = e010.y*omx + e110.y*wx;
        const float c11a = e011.x*omx + e111.x*wx, c11b = e011.y*omx + e111.y*wx;
        const float c0a = c00a*omy + c10a*wy, c0b = c00b*omy + c10b*wy;
        const float c1a = c01a*omy + c11a*wy, c1b = c01b*omy + c11b*wy;
        r[k] = pack_s(c0a*omz + c1a*wz, c0b*omz + c1b*wz);
    }
    if (p0 + 4 <= n) {
        *(uint4*)(wsh + (size_t)lv * n + p0) = make_uint4(r[0], r[1], r[2], r[3]);
    } else {
        for (int k = 0; k < 4 && p0 + k < n; ++k)
            wsh[(size_t)lv * n + p0 + k] = r[k];
    }
}

// ---------------- kernel 2: fp16 SoA -> f32 AoS ---------------------------
__global__ __launch_bounds__(256) void aos_kernel(
    const uint32_t* __restrict__ wsh, float* __restrict__ out, int n)
{
    const int p0 = ((int)blockIdx.x * 256 + (int)threadIdx.x) * 4;
    if (p0 >= n) return;

    if (p0 + 4 <= n) {
        const uint4 v0 = *(const uint4*)(wsh + 0 * (size_t)n + p0);
        const uint4 v1 = *(const uint4*)(wsh + 1 * (size_t)n + p0);
        const uint4 v2 = *(const uint4*)(wsh + 2 * (size_t)n + p0);
        const uint4 v3 = *(const uint4*)(wsh + 3 * (size_t)n + p0);
        const uint4 v4 = *(const uint4*)(wsh + 4 * (size_t)n + p0);
        const uint4 v5 = *(const uint4*)(wsh + 5 * (size_t)n + p0);
        const uint4 v6 = *(const uint4*)(wsh + 6 * (size_t)n + p0);
        const uint4 v7 = *(const uint4*)(wsh + 7 * (size_t)n + p0);
#pragma unroll
        for (int k = 0; k < 4; ++k) {
            const float2 f0 = h2f(getc(v0, k)), f1 = h2f(getc(v1, k));
            const float2 f2 = h2f(getc(v2, k)), f3 = h2f(getc(v3, k));
            const float2 f4 = h2f(getc(v4, k)), f5 = h2f(getc(v5, k));
            const float2 f6 = h2f(getc(v6, k)), f7 = h2f(getc(v7, k));
            float4* __restrict__ op = (float4*)(out + (size_t)(p0 + k) * 16);
            op[0] = make_float4(f0.x*FINV, f0.y*FINV, f1.x*FINV, f1.y*FINV);
            op[1] = make_float4(f2.x*FINV, f2.y*FINV, f3.x*FINV, f3.y*FINV);
            op[2] = make_float4(f4.x*FINV, f4.y*FINV, f5.x*FINV, f5.y*FINV);
            op[3] = make_float4(f6.x*FINV, f6.y*FINV, f7.x*FINV, f7.y*FINV);
        }
    } else {
        for (int k = 0; k < 4 && p0 + k < n; ++k) {
            const int i = p0 + k;
            float* __restrict__ op = out + (size_t)i * 16;
#pragma unroll
            for (int l = 0; l < 8; ++l) {
                const float2 f = h2f(wsh[(size_t)l * n + i]);
                op[2*l + 0] = f.x * FINV;
                op[2*l + 1] = f.y * FINV;
            }
        }
    }
}

// ---------------- fallback: monolithic, f32 exact -------------------------
__global__ __launch_bounds__(256) void hash_embed_mono_kernel(
    const float* __restrict__ x, const float* __restrict__ tables,
    float* __restrict__ out, int n)
{
    const int i = blockIdx.x * 256 + threadIdx.x;
    if (i >= n) return;
    const float px = x[3*i+0], py = x[3*i+1], pz = x[3*i+2];
    const float cx = fminf(fmaxf(px, 0.0f), 1.0f);
    const float cy = fminf(fmaxf(py, 0.0f), 1.0f);
    const float cz = fminf(fmaxf(pz, 0.0f), 1.0f);
    const float resf[8] = {16.f,20.f,25.f,32.f,40.f,50.f,64.f,80.f};
    float o[16];
#pragma unroll
    for (int l = 0; l < 8; ++l) {
        const float R = resf[l], g = 1.0f / R;
        const int bx = (int)floorf(cx*R), by = (int)floorf(cy*R), bz = (int)floorf(cz*R);
        const float wx = (px - bx*g)*R, wy = (py - by*g)*R, wz = (pz - bz*g)*R;
        const uint32_t hx0 = (uint32_t)bx, hx1 = hx0+1u;
        const uint32_t hy0 = (uint32_t)by*P2, hy1 = hy0+P2;
        const uint32_t hz0 = (uint32_t)bz*P3, hz1 = hz0+P3;
        const float2* tab = (const float2*)(tables) + (size_t)l*(size_t)TABLE_SIZE;
        const float2 e000 = tab[(hx0^hy0^hz0)&TMASK], e001 = tab[(hx0^hy0^hz1)&TMASK];
        const float2 e010 = tab[(hx0^hy1^hz0)&TMASK], e011 = tab[(hx0^hy1^hz1)&TMASK];
        const float2 e100 = tab[(hx1^hy0^hz0)&TMASK], e101 = tab[(hx1^hy0^hz1)&TMASK];
        const float2 e110 = tab[(hx1^hy1^hz0)&TMASK], e111 = tab[(hx1^hy1^hz1)&TMASK];
        const float omx = 1.f-wx, omy = 1.f-wy, omz = 1.f-wz;
        const float c00a = e000.x*omx + e100.x*wx, c00b = e000.y*omx + e100.y*wx;
        const float c01a = e001.x*omx + e101.x*wx, c01b = e001.y*omx + e101.y*wx;
        const float c10a = e010.x*omx + e110.x*wx, c10b = e010.y*omx + e110.y*wx;
        const float c11a = e011.x*omx + e111.x*wx, c11b = e011.y*omx + e111.y*wx;
        const float c0a = c00a*omy + c10a*wy, c0b = c00b*omy + c10b*wy;
        const float c1a = c01a*omy + c11a*wy, c1b = c01b*omy + c11b*wy;
        o[2*l+0] = c0a*omz + c1a*wz;
        o[2*l+1] = c0b*omz + c1b*wz;
    }
    float4* op = (float4*)(out + (size_t)i * 16);
    op[0] = make_float4(o[0],o[1],o[2],o[3]);
    op[1] = make_float4(o[4],o[5],o[6],o[7]);
    op[2] = make_float4(o[8],o[9],o[10],o[11]);
    op[3] = make_float4(o[12],o[13],o[14],o[15]);
}

extern "C" void kernel_launch(void* const* d_in, const int* in_sizes, int n_in,
                              void* d_out, int out_size, void* d_ws, size_t ws_size,
                              hipStream_t stream) {
    const float* x = (const float*)d_in[0];
    const float* tables = (const float*)d_in[1];
    float* out = (float*)d_out;
    const int n = in_sizes[0] / 3;  // 1048576 points

    // >64KB dynamic LDS needs opt-in; wsh needs 8*n*4B = 32MB.
    static int cap = -1;
    if (cap < 0) {
        cap = (hipFuncSetAttribute((const void*)embed_lds_kernel,
                  hipFuncAttributeMaxDynamicSharedMemorySize, 140608) == hipSuccess)
              ? 1 : 0;
    }
    const size_t ws_needed = (size_t)8 * (size_t)n * sizeof(uint32_t);  // 32 MB
    if (ws_size < ws_needed || cap == 0) {
        hash_embed_mono_kernel<<<(n + 255) / 256, 256, 0, stream>>>(x, tables, out, n);
        return;
    }

    uint32_t* wsh = (uint32_t*)d_ws;
    float2* dense = (float2*)out;
    uint4*  quads = (uint4*)((char*)out + QUAD_BYTES_OFF);
    uint2*  pairs = (uint2*)((char*)out + PAIR_BYTES_OFF);

    // k0: all derived tables, one launch (grid.y: 4 quad levels, pair7, coarse)
    build_tables_kernel<<<dim3(2051, 6), 256, 0, stream>>>(tables, dense, quads, pairs);

    // LDS-path levels 0..2 (f32-exact compute, fp16 store)
    static const int DIMt[3] = {17, 21, 26};
    static const int Et[3]   = {4913, 9261, 17576};
    static const int OFFt[3] = {0, 4913, 14174};
    const int lgrid = (n + 4095) / 4096;
    for (int lv = 0; lv < 3; ++lv) {
        embed_lds_kernel<<<lgrid, 1024, (size_t)Et[lv] * sizeof(float2), stream>>>(
            x, dense, wsh, n, lv, DIMt[lv], Et[lv], OFFt[lv]);
    }

    // per-level gather: levels 3..7, level-major block order (R12 structure)
    const int bpl = (n + 1023) / 1024;
    embed_levels_kernel<<<5 * bpl, 256, 0, stream>>>(x, quads, pairs, wsh, n, bpl);

    aos_kernel<<<(n + 1023) / 1024, 256, 0, stream>>>(wsh, out, n);
}

// Round 11
// 228.674 us; speedup vs baseline: 1.1176x; 1.1173x over previous
//
#include <hip/hip_runtime.h>
#include <hip/hip_fp16.h>
#include <stdint.h>

// HashEmbedder (Instant-NGP hash grid), MI355X gfx950.
// R14 -> R15. R14: embed 72.2us (MSHR/latency wall: 0.39 VMEM/cyc/CU ~=
// 150 outstanding / ~350cyc; R13 proved occupancy not binding) but total
// stuck at 255.5: ~140us of overhead+gaps+small-kernels across 6 dispatches
// (fixed ~90us + ~5us/dispatch + serial small kernels). R15 collapses to 3
// dispatches: (a) L2 joins the gather kernel as a 260KB fp16 quad table
// (trivially L2-resident); (b) ONE fused final kernel = L0+L1 dense f32 in
// LDS (113KB, exact) + read ws rows 2..7 + write AoS out directly, replacing
// 3 LDS kernels + aos. Dense table lives in ws row 0 (avoids out R/W race).
// Predicted: embed ~80-85us, final ~18-22us, build ~10us, total ~215-230us.

#define TABLE_SIZE (1u << 19)
#define TMASK (TABLE_SIZE - 1u)
#define P2 2654435761u
#define P3 805459861u

#define FSCALE 8192.0f
#define FINV   1.220703125e-4f   // 1/8192, exact pow2

// out scratch (dead after final kernel overwrites):
//   [256KB, ~8.4MB): fp16 quad tables, levels 2..6 (uint4, SCALED x8192)
//   [16MB, ~20.2MB): fp16 pair table, level 7 (uint2, SCALED x8192)
#define QUAD_BYTES_OFF 262144
#define PAIR_BYTES_OFF 16777216

// quad offsets (uint4 units): L2:0 L3:16250 L4:50042 L5:115642 L6:243142
// end 509382 entries (8.15MB)
#define OFF_Q2 0
#define OFF_Q3 16250
#define OFF_Q4 50042
#define OFF_Q5 115642
#define OFF_Q6 243142

// dense f32 tables for L0+L1 live in ws ROW 0 (float2[14174] = 113KB < 4MB)
#define DENSE_L1_OFF 4913
#define DENSE_E 14174
#define DENSE_BYTES (DENSE_E * 8)

__device__ __forceinline__ void quad_geom(int l, float& R, int& DK, int& offq) {
    switch (l) {
        case 2: R=25.f; DK=25; offq=OFF_Q2; break;
        case 3: R=32.f; DK=32; offq=OFF_Q3; break;
        case 4: R=40.f; DK=40; offq=OFF_Q4; break;
        case 5: R=50.f; DK=50; offq=OFF_Q5; break;
        default:R=64.f; DK=64; offq=OFF_Q6; break;
    }
}

__device__ __forceinline__ uint32_t pack_s(float a, float b) {   // scale+pack
    __half2 h = __floats2half2_rn(a * FSCALE, b * FSCALE);
    return *(uint32_t*)&h;
}
__device__ __forceinline__ uint32_t pack_r(float a, float b) {   // raw pack
    __half2 h = __floats2half2_rn(a, b);
    return *(uint32_t*)&h;
}
__device__ __forceinline__ float2 h2f(uint32_t u) {
    __half2 h = *(__half2*)&u;
    return __half22float2(h);
}
__device__ __forceinline__ uint32_t getc(const uint4 v, int k) {
    return k == 0 ? v.x : k == 1 ? v.y : k == 2 ? v.z : v.w;
}

// ---------------- kernel 0: build all derived tables (one launch) ---------
// role (blockIdx.y): 0..4 -> quad level 2+role; 5 -> pair7; 6 -> dense L0+L1
__global__ __launch_bounds__(256) void build_tables_kernel(
    const float* __restrict__ tables, float2* __restrict__ dense,
    uint4* __restrict__ quads, uint2* __restrict__ pairs)
{
    const int role = (int)blockIdx.y;
    const int e = (int)blockIdx.x * 256 + (int)threadIdx.x;

    if (role < 5) {
        float Rf; int DK, offq;
        quad_geom(2 + role, Rf, DK, offq);
        const int l = 2 + role;
        const int E = (DK + 1) * DK * DK;
        if (e >= E) return;
        const int d2 = DK * DK;
        const int i = e / d2;
        const int rem = e - i * d2;
        const int j = rem / DK;
        const int k = rem - j * DK;
        const float2* __restrict__ tab = (const float2*)tables + (size_t)l * (size_t)TABLE_SIZE;
        const uint32_t hx  = (uint32_t)i;
        const uint32_t hy0 = (uint32_t)j * P2, hy1 = hy0 + P2;
        const uint32_t hz0 = (uint32_t)k * P3, hz1 = hz0 + P3;
        const float2 v00 = tab[(hx ^ hy0 ^ hz0) & TMASK];
        const float2 v01 = tab[(hx ^ hy0 ^ hz1) & TMASK];
        const float2 v10 = tab[(hx ^ hy1 ^ hz0) & TMASK];
        const float2 v11 = tab[(hx ^ hy1 ^ hz1) & TMASK];
        uint4 u;
        u.x = pack_s(v00.x, v00.y);
        u.y = pack_s(v01.x, v01.y);
        u.z = pack_s(v10.x, v10.y);
        u.w = pack_s(v11.x, v11.y);
        quads[offq + e] = u;
    } else if (role == 5) {
        const int E = 81 * 81 * 80;     // 524,880
        if (e >= E) return;
        const int i = e / 6480;         // 81*80
        const int rem = e - i * 6480;
        const int j = rem / 80;
        const int k = rem - j * 80;
        const float2* __restrict__ tab = (const float2*)tables + (size_t)7 * (size_t)TABLE_SIZE;
        const uint32_t hb = (uint32_t)i ^ ((uint32_t)j * P2);
        const float2 a = tab[(hb ^ ((uint32_t)k * P3)) & TMASK];
        const float2 b = tab[(hb ^ ((uint32_t)(k + 1) * P3)) & TMASK];
        uint2 u;
        u.x = pack_s(a.x, a.y);
        u.y = pack_s(b.x, b.y);
        pairs[e] = u;
    } else {
        if (e >= DENSE_E) return;       // L0: 4913 (DIM 17), L1: 9261 (DIM 21)
        int lv, DIM, off;
        if (e < 4913) { lv = 0; DIM = 17; off = 0; }
        else          { lv = 1; DIM = 21; off = 4913; }
        const int le = e - off;
        const int d2 = DIM * DIM;
        const int i = le / d2;
        const int rem = le - i * d2;
        const int j = rem / DIM;
        const int k = rem - j * DIM;
        const uint32_t h = ((uint32_t)i ^ ((uint32_t)j * P2) ^ ((uint32_t)k * P3)) & TMASK;
        const float2* __restrict__ tab = (const float2*)tables + (size_t)lv * (size_t)TABLE_SIZE;
        dense[e] = tab[h];
    }
}

// ---------------- single-point tail helpers (packed scaled output) --------
__device__ uint32_t embed_quad_one(int l, const uint4* __restrict__ quads,
                                   float px, float py, float pz) {
    float R; int DK, offq;
    quad_geom(l, R, DK, offq);
    const float g = 1.0f / R;
    const float cx = fminf(fmaxf(px, 0.0f), 1.0f);
    const float cy = fminf(fmaxf(py, 0.0f), 1.0f);
    const float cz = fminf(fmaxf(pz, 0.0f), 1.0f);
    const int bx = min((int)floorf(cx * R), DK - 1);
    const int by = min((int)floorf(cy * R), DK - 1);
    const int bz = min((int)floorf(cz * R), DK - 1);
    const float wx = (px - (float)bx * g) * R;
    const float wy = (py - (float)by * g) * R;
    const float wz = (pz - (float)bz * g) * R;
    const int d2 = DK * DK;
    const int idx = (bx * DK + by) * DK + bz;
    const uint4 qa = quads[offq + idx];
    const uint4 qb = quads[offq + idx + d2];
    const float omx = 1.0f - wx, omy = 1.0f - wy, omz = 1.0f - wz;
    const float2 a00 = h2f(qa.x), a01 = h2f(qa.y), a10 = h2f(qa.z), a11 = h2f(qa.w);
    const float2 b00 = h2f(qb.x), b01 = h2f(qb.y), b10 = h2f(qb.z), b11 = h2f(qb.w);
    const float m00a = a00.x*omx + b00.x*wx, m00b = a00.y*omx + b00.y*wx;
    const float m01a = a01.x*omx + b01.x*wx, m01b = a01.y*omx + b01.y*wx;
    const float m10a = a10.x*omx + b10.x*wx, m10b = a10.y*omx + b10.y*wx;
    const float m11a = a11.x*omx + b11.x*wx, m11b = a11.y*omx + b11.y*wx;
    const float c0a = m00a*omz + m01a*wz, c0b = m00b*omz + m01b*wz;
    const float c1a = m10a*omz + m11a*wz, c1b = m10b*omz + m11b*wz;
    return pack_r(c0a*omy + c1a*wy, c0b*omy + c1b*wy);
}
__device__ uint32_t embed_pair7_one(const uint2* __restrict__ pairs,
                                    float px, float py, float pz) {
    const float R = 80.f, g = 1.0f / R;
    const float cx = fminf(fmaxf(px, 0.0f), 1.0f);
    const float cy = fminf(fmaxf(py, 0.0f), 1.0f);
    const float cz = fminf(fmaxf(pz, 0.0f), 1.0f);
    const int bx = min((int)floorf(cx * R), 79);
    const int by = min((int)floorf(cy * R), 79);
    const int bz = min((int)floorf(cz * R), 79);
    const float wx = (px - (float)bx * g) * R;
    const float wy = (py - (float)by * g) * R;
    const float wz = (pz - (float)bz * g) * R;
    const int idx = (bx * 81 + by) * 80 + bz;
    const uint2 d00 = pairs[idx];
    const uint2 d01 = pairs[idx + 80];
    const uint2 d10 = pairs[idx + 6480];
    const uint2 d11 = pairs[idx + 6560];
    const float omx = 1.0f - wx, omy = 1.0f - wy, omz = 1.0f - wz;
    const float2 a00 = h2f(d00.x), z00 = h2f(d00.y);
    const float2 a01 = h2f(d01.x), z01 = h2f(d01.y);
    const float2 a10 = h2f(d10.x), z10 = h2f(d10.y);
    const float2 a11 = h2f(d11.x), z11 = h2f(d11.y);
    const float c00a = a00.x*omz + z00.x*wz, c00b = a00.y*omz + z00.y*wz;
    const float c01a = a01.x*omz + z01.x*wz, c01b = a01.y*omz + z01.y*wz;
    const float c10a = a10.x*omz + z10.x*wz, c10b = a10.y*omz + z10.y*wz;
    const float c11a = a11.x*omz + z11.x*wz, c11b = a11.y*omz + z11.y*wz;
    const float e0a = c00a*omy + c01a*wy, e0b = c00b*omy + c01b*wy;
    const float e1a = c10a*omy + c11a*wy, e1b = c10b*omy + c11b*wy;
    return pack_r(e0a*omx + e1a*wx, e0b*omx + e1b*wx);
}

// ---------------- kernel 1: per-level gather embed (levels 2..7) ----------
// One level per block range (level-major -> table L2-resident chip-wide).
// Thread -> 4 consecutive points; transient state only (VGPR-light).
// Levels 2..6: 2 fp16-quad gathers/pt; level 7: 4 pair gathers/pt.
__global__ __launch_bounds__(256, 4) void embed_levels_kernel(
    const float* __restrict__ x, const uint4* __restrict__ quads,
    const uint2* __restrict__ pairs, uint32_t* __restrict__ wsh,
    int n, int bpl)
{
    const int bid = (int)blockIdx.x;
    const int q = bid / bpl;
    const int l = 2 + q;
    const int pb = bid - q * bpl;
    const int p0 = pb * 1024 + 4 * (int)threadIdx.x;
    if (p0 >= n) return;

    uint32_t* __restrict__ wl = wsh + (size_t)l * (size_t)n;

    if (p0 + 4 > n) {           // rare tail
        for (int pp = 0; pp < 4; ++pp) {
            const int i = p0 + pp;
            if (i >= n) break;
            const float px = x[3*i], py = x[3*i+1], pz = x[3*i+2];
            wl[i] = (l < 7) ? embed_quad_one(l, quads, px, py, pz)
                            : embed_pair7_one(pairs, px, py, pz);
        }
        return;
    }

    // 3 vector loads cover 4 points
    const float4* __restrict__ xv = (const float4*)(x + (size_t)3 * p0);
    const float4 f0 = xv[0], f1 = xv[1], f2 = xv[2];
    const float px0 = f0.x, py0 = f0.y, pz0 = f0.z;
    const float px1 = f0.w, py1 = f1.x, pz1 = f1.y;
    const float px2 = f1.z, py2 = f1.w, pz2 = f2.x;
    const float px3 = f2.y, py3 = f2.z, pz3 = f2.w;

    uint32_t r0, r1, r2, r3;

    if (l < 7) {
        // ---------------- quad path ----------------
        float R; int DK, offq;
        quad_geom(l, R, DK, offq);
        const float g = 1.0f / R;
        const int bmax = DK - 1;
        const int d2 = DK * DK;
        const uint4* __restrict__ tab = quads + offq;

#define QPREP(k) \
        const float cx##k = fminf(fmaxf(px##k, 0.0f), 1.0f); \
        const float cy##k = fminf(fmaxf(py##k, 0.0f), 1.0f); \
        const float cz##k = fminf(fmaxf(pz##k, 0.0f), 1.0f); \
        const int bx##k = min((int)floorf(cx##k * R), bmax); \
        const int by##k = min((int)floorf(cy##k * R), bmax); \
        const int bz##k = min((int)floorf(cz##k * R), bmax); \
        const float wx##k = (px##k - (float)bx##k * g) * R; \
        const float wy##k = (py##k - (float)by##k * g) * R; \
        const float wz##k = (pz##k - (float)bz##k * g) * R; \
        const int ia##k = (bx##k * DK + by##k) * DK + bz##k; \
        const int ib##k = ia##k + d2;

        QPREP(0) QPREP(1) QPREP(2) QPREP(3)

#define QGATHER(k) \
        const uint4 qa##k = tab[ia##k]; \
        const uint4 qb##k = tab[ib##k];

        QGATHER(0) QGATHER(1) QGATHER(2) QGATHER(3)

#define QINTERP(k, dst) { \
        const float omx = 1.0f - wx##k, omy = 1.0f - wy##k, omz = 1.0f - wz##k; \
        const float2 a00 = h2f(qa##k.x), a01 = h2f(qa##k.y); \
        const float2 a10 = h2f(qa##k.z), a11 = h2f(qa##k.w); \
        const float2 b00 = h2f(qb##k.x), b01 = h2f(qb##k.y); \
        const float2 b10 = h2f(qb##k.z), b11 = h2f(qb##k.w); \
        const float m00a = a00.x*omx + b00.x*wx##k, m00b = a00.y*omx + b00.y*wx##k; \
        const float m01a = a01.x*omx + b01.x*wx##k, m01b = a01.y*omx + b01.y*wx##k; \
        const float m10a = a10.x*omx + b10.x*wx##k, m10b = a10.y*omx + b10.y*wx##k; \
        const float m11a = a11.x*omx + b11.x*wx##k, m11b = a11.y*omx + b11.y*wx##k; \
        const float c0a = m00a*omz + m01a*wz##k, c0b = m00b*omz + m01b*wz##k; \
        const float c1a = m10a*omz + m11a*wz##k, c1b = m10b*omz + m11b*wz##k; \
        dst = pack_r(c0a*omy + c1a*wy##k, c0b*omy + c1b*wy##k); }

        QINTERP(0, r0) QINTERP(1, r1) QINTERP(2, r2) QINTERP(3, r3)
    } else {
        // ---------------- pair path (level 7, R=80) ----------------
        const float R = 80.f, g = 1.0f / R;

#define SPREP(k) \
        const float cx##k = fminf(fmaxf(px##k, 0.0f), 1.0f); \
        const float cy##k = fminf(fmaxf(py##k, 0.0f), 1.0f); \
        const float cz##k = fminf(fmaxf(pz##k, 0.0f), 1.0f); \
        const int bx##k = min((int)floorf(cx##k * R), 79); \
        const int by##k = min((int)floorf(cy##k * R), 79); \
        const int bz##k = min((int)floorf(cz##k * R), 79); \
        const float wx##k = (px##k - (float)bx##k * g) * R; \
        const float wy##k = (py##k - (float)by##k * g) * R; \
        const float wz##k = (pz##k - (float)bz##k * g) * R; \
        const int ix##k = (bx##k * 81 + by##k) * 80 + bz##k;

        SPREP(0) SPREP(1) SPREP(2) SPREP(3)

#define SGATHER(k) \
        const uint2 d00##k = pairs[ix##k]; \
        const uint2 d01##k = pairs[ix##k + 80]; \
        const uint2 d10##k = pairs[ix##k + 6480]; \
        const uint2 d11##k = pairs[ix##k + 6560];

        SGATHER(0) SGATHER(1) SGATHER(2) SGATHER(3)

#define SINTERP(k, dst) { \
        const float omx = 1.0f - wx##k, omy = 1.0f - wy##k, omz = 1.0f - wz##k; \
        const float2 a00 = h2f(d00##k.x), z00 = h2f(d00##k.y); \
        const float2 a01 = h2f(d01##k.x), z01 = h2f(d01##k.y); \
        const float2 a10 = h2f(d10##k.x), z10 = h2f(d10##k.y); \
        const float2 a11 = h2f(d11##k.x), z11 = h2f(d11##k.y); \
        const float c00a = a00.x*omz + z00.x*wz##k, c00b = a00.y*omz + z00.y*wz##k; \
        const float c01a = a01.x*omz + z01.x*wz##k, c01b = a01.y*omz + z01.y*wz##k; \
        const float c10a = a10.x*omz + z10.x*wz##k, c10b = a10.y*omz + z10.y*wz##k; \
        const float c11a = a11.x*omz + z11.x*wz##k, c11b = a11.y*omz + z11.y*wz##k; \
        const float e0a = c00a*omy + c01a*wy##k, e0b = c00b*omy + c01b*wy##k; \
        const float e1a = c10a*omy + c11a*wy##k, e1b = c10b*omy + c11b*wy##k; \
        dst = pack_r(e0a*omx + e1a*wx##k, e0b*omx + e1b*wx##k); }

        SINTERP(0, r0) SINTERP(1, r1) SINTERP(2, r2) SINTERP(3, r3)
    }

    *(uint4*)(wl + p0) = make_uint4(r0, r1, r2, r3);
}

// ---------------- kernel 2: fused final (L0+L1 LDS + rows 2..7 -> AoS) ----
// L0+L1 dense f32 staged in 113KB LDS (exact); per thread: 4 points, 3 x
// loads, 6 uint4 ws loads, 16 f4 stores. Replaces 3 LDS kernels + aos.
__global__ __launch_bounds__(1024) void final_kernel(
    const float* __restrict__ x, const uint32_t* wsh,
    float* __restrict__ out, int n)
{
    extern __shared__ float2 lds[];           // 14174 float2 (L0 then L1)
    const float2* dense = (const float2*)wsh; // ws row 0
    for (int e = (int)threadIdx.x; e < DENSE_E; e += 1024) lds[e] = dense[e];
    __syncthreads();

    const int p0 = ((int)blockIdx.x * 1024 + (int)threadIdx.x) * 4;
    if (p0 >= n) return;

    float px[4], py[4], pz[4];
    if (p0 + 4 <= n) {
        const float4* __restrict__ xv = (const float4*)(x + (size_t)3 * p0);
        const float4 f0 = xv[0], f1 = xv[1], f2 = xv[2];
        px[0] = f0.x; py[0] = f0.y; pz[0] = f0.z;
        px[1] = f0.w; py[1] = f1.x; pz[1] = f1.y;
        px[2] = f1.z; py[2] = f1.w; pz[2] = f2.x;
        px[3] = f2.y; py[3] = f2.z; pz[3] = f2.w;
    } else {
#pragma unroll
        for (int k = 0; k < 4; ++k) {
            const int i = min(p0 + k, n - 1);
            px[k] = x[3*i]; py[k] = x[3*i+1]; pz[k] = x[3*i+2];
        }
    }

    // issue the 6 ws row loads early (independent of LDS compute)
    uint4 v[6];
    if (p0 + 4 <= n) {
#pragma unroll
        for (int l = 0; l < 6; ++l)
            v[l] = *(const uint4*)(wsh + (size_t)(l + 2) * n + p0);
    } else {
#pragma unroll
        for (int l = 0; l < 6; ++l) {
            uint4 t;
            t.x = wsh[(size_t)(l+2)*n + min(p0+0, n-1)];
            t.y = wsh[(size_t)(l+2)*n + min(p0+1, n-1)];
            t.z = wsh[(size_t)(l+2)*n + min(p0+2, n-1)];
            t.w = wsh[(size_t)(l+2)*n + min(p0+3, n-1)];
            v[l] = t;
        }
    }

    // L0 (DIM 17) and L1 (DIM 21) exact f32 from LDS
    float l0a[4], l0b[4], l1a[4], l1b[4];
#pragma unroll
    for (int k = 0; k < 4; ++k) {
#pragma unroll
        for (int lv = 0; lv < 2; ++lv) {
            const float R = (lv == 0) ? 16.f : 20.f;
            const int DIM = (lv == 0) ? 17 : 21;
            const int off = (lv == 0) ? 0 : DENSE_L1_OFF;
            const float g = 1.0f / R;
            const int D2 = DIM * DIM;
            const int bmax = DIM - 2;
            const float cx = fminf(fmaxf(px[k], 0.0f), 1.0f);
            const float cy = fminf(fmaxf(py[k], 0.0f), 1.0f);
            const float cz = fminf(fmaxf(pz[k], 0.0f), 1.0f);
            const int bx = min((int)floorf(cx * R), bmax);
            const int by = min((int)floorf(cy * R), bmax);
            const int bz = min((int)floorf(cz * R), bmax);
            const float wx = (px[k] - (float)bx * g) * R;
            const float wy = (py[k] - (float)by * g) * R;
            const float wz = (pz[k] - (float)bz * g) * R;
            const int c = off + (bx * DIM + by) * DIM + bz;
            const float2 e000 = lds[c];
            const float2 e001 = lds[c + 1];
            const float2 e010 = lds[c + DIM];
            const float2 e011 = lds[c + DIM + 1];
            const float2 e100 = lds[c + D2];
            const float2 e101 = lds[c + D2 + 1];
            const float2 e110 = lds[c + D2 + DIM];
            const float2 e111 = lds[c + D2 + DIM + 1];
            const float omx = 1.0f - wx, omy = 1.0f - wy, omz = 1.0f - wz;
            const float c00a = e000.x*omx + e100.x*wx, c00b = e000.y*omx + e100.y*wx;
            const float c01a = e001.x*omx + e101.x*wx, c01b = e001.y*omx + e101.y*wx;
            const float c10a = e010.x*omx + e110.x*wx, c10b = e010.y*omx + e110.y*wx;
            const float c11a = e011.x*omx + e111.x*wx, c11b = e011.y*omx + e111.y*wx;
            const float c0a = c00a*omy + c10a*wy, c0b = c00b*omy + c10b*wy;
            const float c1a = c01a*omy + c11a*wy, c1b = c01b*omy + c11b*wy;
            if (lv == 0) { l0a[k] = c0a*omz + c1a*wz; l0b[k] = c0b*omz + c1b*wz; }
            else         { l1a[k] = c0a*omz + c1a*wz; l1b[k] = c0b*omz + c1b*wz; }
        }
    }

    // write AoS output
#pragma unroll
    for (int k = 0; k < 4; ++k) {
        if (p0 + k >= n) break;
        const float2 f2v = h2f(getc(v[0], k)), f3v = h2f(getc(v[1], k));
        const float2 f4v = h2f(getc(v[2], k)), f5v = h2f(getc(v[3], k));
        const float2 f6v = h2f(getc(v[4], k)), f7v = h2f(getc(v[5], k));
        float4* __restrict__ op = (float4*)(out + (size_t)(p0 + k) * 16);
        op[0] = make_float4(l0a[k], l0b[k], l1a[k], l1b[k]);
        op[1] = make_float4(f2v.x*FINV, f2v.y*FINV, f3v.x*FINV, f3v.y*FINV);
        op[2] = make_float4(f4v.x*FINV, f4v.y*FINV, f5v.x*FINV, f5v.y*FINV);
        op[3] = make_float4(f6v.x*FINV, f6v.y*FINV, f7v.x*FINV, f7v.y*FINV);
    }
}

// ---------------- fallback: monolithic, f32 exact -------------------------
__global__ __launch_bounds__(256) void hash_embed_mono_kernel(
    const float* __restrict__ x, const float* __restrict__ tables,
    float* __restrict__ out, int n)
{
    const int i = blockIdx.x * 256 + threadIdx.x;
    if (i >= n) return;
    const float px = x[3*i+0], py = x[3*i+1], pz = x[3*i+2];
    const float cx = fminf(fmaxf(px, 0.0f), 1.0f);
    const float cy = fminf(fmaxf(py, 0.0f), 1.0f);
    const float cz = fminf(fmaxf(pz, 0.0f), 1.0f);
    const float resf[8] = {16.f,20.f,25.f,32.f,40.f,50.f,64.f,80.f};
    float o[16];
#pragma unroll
    for (int l = 0; l < 8; ++l) {
        const float R = resf[l], g = 1.0f / R;
        const int bx = (int)floorf(cx*R), by = (int)floorf(cy*R), bz = (int)floorf(cz*R);
        const float wx = (px - bx*g)*R, wy = (py - by*g)*R, wz = (pz - bz*g)*R;
        const uint32_t hx0 = (uint32_t)bx, hx1 = hx0+1u;
        const uint32_t hy0 = (uint32_t)by*P2, hy1 = hy0+P2;
        const uint32_t hz0 = (uint32_t)bz*P3, hz1 = hz0+P3;
        const float2* tab = (const float2*)(tables) + (size_t)l*(size_t)TABLE_SIZE;
        const float2 e000 = tab[(hx0^hy0^hz0)&TMASK], e001 = tab[(hx0^hy0^hz1)&TMASK];
        const float2 e010 = tab[(hx0^hy1^hz0)&TMASK], e011 = tab[(hx0^hy1^hz1)&TMASK];
        const float2 e100 = tab[(hx1^hy0^hz0)&TMASK], e101 = tab[(hx1^hy0^hz1)&TMASK];
        const float2 e110 = tab[(hx1^hy1^hz0)&TMASK], e111 = tab[(hx1^hy1^hz1)&TMASK];
        const float omx = 1.f-wx, omy = 1.f-wy, omz = 1.f-wz;
        const float c00a = e000.x*omx + e100.x*wx, c00b = e000.y*omx + e100.y*wx;
        const float c01a = e001.x*omx + e101.x*wx, c01b = e001.y*omx + e101.y*wx;
        const float c10a = e010.x*omx + e110.x*wx, c10b = e010.y*omx + e110.y*wx;
        const float c11a = e011.x*omx + e111.x*wx, c11b = e011.y*omx + e111.y*wx;
        const float c0a = c00a*omy + c10a*wy, c0b = c00b*omy + c10b*wy;
        const float c1a = c01a*omy + c11a*wy, c1b = c01b*omy + c11b*wy;
        o[2*l+0] = c0a*omz + c1a*wz;
        o[2*l+1] = c0b*omz + c1b*wz;
    }
    float4* op = (float4*)(out + (size_t)i * 16);
    op[0] = make_float4(o[0],o[1],o[2],o[3]);
    op[1] = make_float4(o[4],o[5],o[6],o[7]);
    op[2] = make_float4(o[8],o[9],o[10],o[11]);
    op[3] = make_float4(o[12],o[13],o[14],o[15]);
}

extern "C" void kernel_launch(void* const* d_in, const int* in_sizes, int n_in,
                              void* d_out, int out_size, void* d_ws, size_t ws_size,
                              hipStream_t stream) {
    const float* x = (const float*)d_in[0];
    const float* tables = (const float*)d_in[1];
    float* out = (float*)d_out;
    const int n = in_sizes[0] / 3;  // 1048576 points

    // 113KB dynamic LDS needs opt-in; wsh needs 8*n*4B = 32MB.
    static int cap = -1;
    if (cap < 0) {
        cap = (hipFuncSetAttribute((const void*)final_kernel,
                  hipFuncAttributeMaxDynamicSharedMemorySize, DENSE_BYTES) == hipSuccess)
              ? 1 : 0;
    }
    const size_t ws_needed = (size_t)8 * (size_t)n * sizeof(uint32_t);  // 32 MB
    if (ws_size < ws_needed || cap == 0) {
        hash_embed_mono_kernel<<<(n + 255) / 256, 256, 0, stream>>>(x, tables, out, n);
        return;
    }

    uint32_t* wsh = (uint32_t*)d_ws;
    float2* dense = (float2*)d_ws;  // ws row 0 (113KB of 4MB row, rows 2..7 used by embed)
    uint4*  quads = (uint4*)((char*)out + QUAD_BYTES_OFF);
    uint2*  pairs = (uint2*)((char*)out + PAIR_BYTES_OFF);

    // k0: all derived tables, one launch (grid.y: 5 quad levels, pair7, dense)
    build_tables_kernel<<<dim3(2051, 7), 256, 0, stream>>>(tables, dense, quads, pairs);

    // k1: per-level gather, levels 2..7, level-major block order
    const int bpl = (n + 1023) / 1024;
    embed_levels_kernel<<<6 * bpl, 256, 0, stream>>>(x, quads, pairs, wsh, n, bpl);

    // k2: fused final (L0+L1 in LDS + unpack rows 2..7 -> AoS out)
    final_kernel<<<(n + 4095) / 4096, 1024, DENSE_BYTES, stream>>>(x, wsh, out, n);
}

// Round 14
// 217.098 us; speedup vs baseline: 1.1772x; 1.0533x over previous
//
#include <hip/hip_runtime.h>
#include <hip/hip_fp16.h>
#include <stdint.h>

// HashEmbedder (Instant-NGP hash grid), MI355X gfx950.
// R15 -> R16 (3rd submit; two GPUAcquisitionTimeouts — never ran).
// R15: 228.7us (embed 82.3 + build ~8 + final ~22 + ~116 fixed).
// Wall model firmed: per-CU lane-request rate ~0.39-0.40 req/cyc/CU,
// OCCUPANCY-INSENSITIVE (R13 26.7% occ == R15 62% occ rate) -> TCP/MSHR
// per-CU limit; only lever is REQUEST COUNT. R16 cuts 20M -> 16.25M:
// (a) L2 moves to final's LDS as fp16 dense (L0+L1+L2 = 127KB fits 160KB);
// (b) embed pairs levels (3,4) SEQUENTIALLY (transient state, not R13's
// concurrent mistake; tables 1.57MB co-resident; x loaded once).
// Predicted: embed ~67-70us, final ~22-25us, total ~210-220us.

#define TABLE_SIZE (1u << 19)
#define TMASK (TABLE_SIZE - 1u)
#define P2 2654435761u
#define P3 805459861u

#define FSCALE 8192.0f
#define FINV   1.220703125e-4f   // 1/8192, exact pow2

// out scratch (dead after final kernel overwrites):
//   [256KB, ~8.1MB): fp16 quad tables, levels 3..6 (uint4, SCALED x8192)
//   [16MB, ~20.2MB): fp16 pair table, level 7 (uint2, SCALED x8192)
#define QUAD_BYTES_OFF 262144
#define PAIR_BYTES_OFF 16777216

// quad offsets (uint4 units): L3:0 L4:33792 L5:99392 L6:226892 end 493132
#define OFF_Q3 0
#define OFF_Q4 33792
#define OFF_Q5 99392
#define OFF_Q6 226892

// fp16 dense tables L0+L1+L2 (packed scaled __half2 as uint32), in ws row 0:
// L0: [0,4913) DIM17, L1: [4913,14174) DIM21, L2: [14174,31750) DIM26
#define DENSE_L1_OFF 4913
#define DENSE_L2_OFF 14174
#define DENSE_E 31750
#define DENSE_BYTES (DENSE_E * 4)   // 127,000 B LDS

__device__ __forceinline__ uint32_t pack_s(float a, float b) {   // scale+pack
    __half2 h = __floats2half2_rn(a * FSCALE, b * FSCALE);
    return *(uint32_t*)&h;
}
__device__ __forceinline__ uint32_t pack_r(float a, float b) {   // raw pack
    __half2 h = __floats2half2_rn(a, b);
    return *(uint32_t*)&h;
}
__device__ __forceinline__ float2 h2f(uint32_t u) {
    __half2 h = *(__half2*)&u;
    return __half22float2(h);
}
__device__ __forceinline__ uint32_t getc(const uint4 v, int k) {
    return k == 0 ? v.x : k == 1 ? v.y : k == 2 ? v.z : v.w;
}

__device__ __forceinline__ void quad_geom(int l, float& R, int& DK, int& offq) {
    switch (l) {
        case 3: R=32.f; DK=32; offq=OFF_Q3; break;
        case 4: R=40.f; DK=40; offq=OFF_Q4; break;
        case 5: R=50.f; DK=50; offq=OFF_Q5; break;
        default:R=64.f; DK=64; offq=OFF_Q6; break;
    }
}

// ---------------- kernel 0: build all derived tables (one launch) ---------
// role (blockIdx.y): 0..3 -> quad level 3+role; 4 -> pair7; 5 -> dense fp16
__global__ __launch_bounds__(256) void build_tables_kernel(
    const float* __restrict__ tables, uint32_t* __restrict__ dense,
    uint4* __restrict__ quads, uint2* __restrict__ pairs)
{
    const int role = (int)blockIdx.y;
    const int e = (int)blockIdx.x * 256 + (int)threadIdx.x;

    if (role < 4) {
        float Rf; int DK, offq;
        quad_geom(3 + role, Rf, DK, offq);
        const int l = 3 + role;
        const int E = (DK + 1) * DK * DK;
        if (e >= E) return;
        const int d2 = DK * DK;
        const int i = e / d2;
        const int rem = e - i * d2;
        const int j = rem / DK;
        const int k = rem - j * DK;
        const float2* __restrict__ tab = (const float2*)tables + (size_t)l * (size_t)TABLE_SIZE;
        const uint32_t hx  = (uint32_t)i;
        const uint32_t hy0 = (uint32_t)j * P2, hy1 = hy0 + P2;
        const uint32_t hz0 = (uint32_t)k * P3, hz1 = hz0 + P3;
        const float2 v00 = tab[(hx ^ hy0 ^ hz0) & TMASK];
        const float2 v01 = tab[(hx ^ hy0 ^ hz1) & TMASK];
        const float2 v10 = tab[(hx ^ hy1 ^ hz0) & TMASK];
        const float2 v11 = tab[(hx ^ hy1 ^ hz1) & TMASK];
        uint4 u;
        u.x = pack_s(v00.x, v00.y);
        u.y = pack_s(v01.x, v01.y);
        u.z = pack_s(v10.x, v10.y);
        u.w = pack_s(v11.x, v11.y);
        quads[offq + e] = u;
    } else if (role == 4) {
        const int E = 81 * 81 * 80;     // 524,880
        if (e >= E) return;
        const int i = e / 6480;         // 81*80
        const int rem = e - i * 6480;
        const int j = rem / 80;
        const int k = rem - j * 80;
        const float2* __restrict__ tab = (const float2*)tables + (size_t)7 * (size_t)TABLE_SIZE;
        const uint32_t hb = (uint32_t)i ^ ((uint32_t)j * P2);
        const float2 a = tab[(hb ^ ((uint32_t)k * P3)) & TMASK];
        const float2 b = tab[(hb ^ ((uint32_t)(k + 1) * P3)) & TMASK];
        uint2 u;
        u.x = pack_s(a.x, a.y);
        u.y = pack_s(b.x, b.y);
        pairs[e] = u;
    } else {
        if (e >= DENSE_E) return;
        int lv, DIM, off;
        if (e < DENSE_L1_OFF)      { lv = 0; DIM = 17; off = 0; }
        else if (e < DENSE_L2_OFF) { lv = 1; DIM = 21; off = DENSE_L1_OFF; }
        else                       { lv = 2; DIM = 26; off = DENSE_L2_OFF; }
        const int le = e - off;
        const int d2 = DIM * DIM;
        const int i = le / d2;
        const int rem = le - i * d2;
        const int j = rem / DIM;
        const int k = rem - j * DIM;
        const uint32_t h = ((uint32_t)i ^ ((uint32_t)j * P2) ^ ((uint32_t)k * P3)) & TMASK;
        const float2* __restrict__ tab = (const float2*)tables + (size_t)lv * (size_t)TABLE_SIZE;
        const float2 v = tab[h];
        dense[e] = pack_s(v.x, v.y);
    }
}

// ---------------- 4-point quad embed (issue-all-then-interp, transient) ---
template<int DK>
__device__ __forceinline__ uint4 embed_quad4(const uint4* __restrict__ tab,
        const float px[4], const float py[4], const float pz[4])
{
    const float R = (float)DK;
    const float g = 1.0f / R;
    const int d2 = DK * DK;
    uint4 qa[4], qb[4];
    float wx[4], wy[4], wz[4];
#pragma unroll
    for (int k = 0; k < 4; ++k) {
        const float cx = fminf(fmaxf(px[k], 0.0f), 1.0f);
        const float cy = fminf(fmaxf(py[k], 0.0f), 1.0f);
        const float cz = fminf(fmaxf(pz[k], 0.0f), 1.0f);
        const int bx = min((int)floorf(cx * R), DK - 1);
        const int by = min((int)floorf(cy * R), DK - 1);
        const int bz = min((int)floorf(cz * R), DK - 1);
        wx[k] = (px[k] - (float)bx * g) * R;
        wy[k] = (py[k] - (float)by * g) * R;
        wz[k] = (pz[k] - (float)bz * g) * R;
        const int ia = (bx * DK + by) * DK + bz;
        qa[k] = tab[ia];
        qb[k] = tab[ia + d2];
    }
    uint32_t r[4];
#pragma unroll
    for (int k = 0; k < 4; ++k) {
        const float omx = 1.0f - wx[k], omy = 1.0f - wy[k], omz = 1.0f - wz[k];
        const float2 a00 = h2f(qa[k].x), a01 = h2f(qa[k].y);
        const float2 a10 = h2f(qa[k].z), a11 = h2f(qa[k].w);
        const float2 b00 = h2f(qb[k].x), b01 = h2f(qb[k].y);
        const float2 b10 = h2f(qb[k].z), b11 = h2f(qb[k].w);
        const float m00a = a00.x*omx + b00.x*wx[k], m00b = a00.y*omx + b00.y*wx[k];
        const float m01a = a01.x*omx + b01.x*wx[k], m01b = a01.y*omx + b01.y*wx[k];
        const float m10a = a10.x*omx + b10.x*wx[k], m10b = a10.y*omx + b10.y*wx[k];
        const float m11a = a11.x*omx + b11.x*wx[k], m11b = a11.y*omx + b11.y*wx[k];
        const float c0a = m00a*omz + m01a*wz[k], c0b = m00b*omz + m01b*wz[k];
        const float c1a = m10a*omz + m11a*wz[k], c1b = m10b*omz + m11b*wz[k];
        r[k] = pack_r(c0a*omy + c1a*wy[k], c0b*omy + c1b*wy[k]);
    }
    return make_uint4(r[0], r[1], r[2], r[3]);
}

__device__ __forceinline__ uint4 embed_pair4(const uint2* __restrict__ pairs,
        const float px[4], const float py[4], const float pz[4])
{
    const float R = 80.f, g = 1.0f / R;
    uint2 d00[4], d01[4], d10[4], d11[4];
    float wx[4], wy[4], wz[4];
#pragma unroll
    for (int k = 0; k < 4; ++k) {
        const float cx = fminf(fmaxf(px[k], 0.0f), 1.0f);
        const float cy = fminf(fmaxf(py[k], 0.0f), 1.0f);
        const float cz = fminf(fmaxf(pz[k], 0.0f), 1.0f);
        const int bx = min((int)floorf(cx * R), 79);
        const int by = min((int)floorf(cy * R), 79);
        const int bz = min((int)floorf(cz * R), 79);
        wx[k] = (px[k] - (float)bx * g) * R;
        wy[k] = (py[k] - (float)by * g) * R;
        wz[k] = (pz[k] - (float)bz * g) * R;
        const int ix = (bx * 81 + by) * 80 + bz;
        d00[k] = pairs[ix];
        d01[k] = pairs[ix + 80];
        d10[k] = pairs[ix + 6480];
        d11[k] = pairs[ix + 6560];
    }
    uint32_t r[4];
#pragma unroll
    for (int k = 0; k < 4; ++k) {
        const float omx = 1.0f - wx[k], omy = 1.0f - wy[k], omz = 1.0f - wz[k];
        const float2 a00 = h2f(d00[k].x), z00 = h2f(d00[k].y);
        const float2 a01 = h2f(d01[k].x), z01 = h2f(d01[k].y);
        const float2 a10 = h2f(d10[k].x), z10 = h2f(d10[k].y);
        const float2 a11 = h2f(d11[k].x), z11 = h2f(d11[k].y);
        const float c00a = a00.x*omz + z00.x*wz[k], c00b = a00.y*omz + z00.y*wz[k];
        const float c01a = a01.x*omz + z01.x*wz[k], c01b = a01.y*omz + z01.y*wz[k];
        const float c10a = a10.x*omz + z10.x*wz[k], c10b = a10.y*omz + z10.y*wz[k];
        const float c11a = a11.x*omz + z11.x*wz[k], c11b = a11.y*omz + z11.y*wz[k];
        const float e0a = c00a*omy + c01a*wy[k], e0b = c00b*omy + c01b*wy[k];
        const float e1a = c10a*omy + c11a*wy[k], e1b = c10b*omy + c11b*wy[k];
        r[k] = pack_r(e0a*omx + e1a*wx[k], e0b*omx + e1b*wx[k]);
    }
    return make_uint4(r[0], r[1], r[2], r[3]);
}

// ---------------- kernel 1: per-group gather embed ------------------------
// group 0: levels 3 THEN 4 sequentially (tables co-resident 1.57MB; x loaded
// once). group 1: level 5. group 2: level 6. group 3: level 7 (pairs).
// Group-major block order -> active table set L2-resident chip-wide.
__global__ __launch_bounds__(256, 4) void embed_levels_kernel(
    const float* __restrict__ x, const uint4* __restrict__ quads,
    const uint2* __restrict__ pairs, uint32_t* __restrict__ wsh,
    int n, int bpl)
{
    const int bid = (int)blockIdx.x;
    const int grp = bid / bpl;
    const int pb = bid - grp * bpl;
    const int p0 = pb * 1024 + 4 * (int)threadIdx.x;
    if (p0 >= n) return;

    float px[4], py[4], pz[4];
    if (p0 + 4 <= n) {
        const float4* __restrict__ xv = (const float4*)(x + (size_t)3 * p0);
        const float4 f0 = xv[0], f1 = xv[1], f2 = xv[2];
        px[0] = f0.x; py[0] = f0.y; pz[0] = f0.z;
        px[1] = f0.w; py[1] = f1.x; pz[1] = f1.y;
        px[2] = f1.z; py[2] = f1.w; pz[2] = f2.x;
        px[3] = f2.y; py[3] = f2.z; pz[3] = f2.w;
    } else {
#pragma unroll
        for (int k = 0; k < 4; ++k) {
            const int i = min(p0 + k, n - 1);
            px[k] = x[3*i]; py[k] = x[3*i+1]; pz[k] = x[3*i+2];
        }
    }

    const int nstore = min(4, n - p0);

#define STORE_ROW(l, r) { \
    uint32_t* __restrict__ wl = wsh + (size_t)(l) * (size_t)n; \
    if (nstore == 4) *(uint4*)(wl + p0) = (r); \
    else for (int k = 0; k < nstore; ++k) wl[p0 + k] = getc((r), k); }

    if (grp == 0) {
        const uint4 r3 = embed_quad4<32>(quads + OFF_Q3, px, py, pz);
        STORE_ROW(3, r3)
        const uint4 r4 = embed_quad4<40>(quads + OFF_Q4, px, py, pz);
        STORE_ROW(4, r4)
    } else if (grp == 1) {
        const uint4 r5 = embed_quad4<50>(quads + OFF_Q5, px, py, pz);
        STORE_ROW(5, r5)
    } else if (grp == 2) {
        const uint4 r6 = embed_quad4<64>(quads + OFF_Q6, px, py, pz);
        STORE_ROW(6, r6)
    } else {
        const uint4 r7 = embed_pair4(pairs, px, py, pz);
        STORE_ROW(7, r7)
    }
}

// ---------------- kernel 2: fused final (L0+L1+L2 LDS + rows 3..7 -> AoS) -
// 127KB fp16 dense in LDS; per thread: 4 points, 3 x loads, 5 uint4 ws
// loads, 16 f4 stores.
__global__ __launch_bounds__(1024) void final_kernel(
    const float* __restrict__ x, const uint32_t* wsh,
    float* __restrict__ out, int n)
{
    extern __shared__ uint32_t lds[];         // 31750 packed fp16 pairs
    for (int e = (int)threadIdx.x; e < DENSE_E; e += 1024) lds[e] = wsh[e];
    __syncthreads();

    const int p0 = ((int)blockIdx.x * 1024 + (int)threadIdx.x) * 4;
    if (p0 >= n) return;

    float px[4], py[4], pz[4];
    if (p0 + 4 <= n) {
        const float4* __restrict__ xv = (const float4*)(x + (size_t)3 * p0);
        const float4 f0 = xv[0], f1 = xv[1], f2 = xv[2];
        px[0] = f0.x; py[0] = f0.y; pz[0] = f0.z;
        px[1] = f0.w; py[1] = f1.x; pz[1] = f1.y;
        px[2] = f1.z; py[2] = f1.w; pz[2] = f2.x;
        px[3] = f2.y; py[3] = f2.z; pz[3] = f2.w;
    } else {
#pragma unroll
        for (int k = 0; k < 4; ++k) {
            const int i = min(p0 + k, n - 1);
            px[k] = x[3*i]; py[k] = x[3*i+1]; pz[k] = x[3*i+2];
        }
    }

    // issue the 5 ws row loads early (independent of LDS compute)
    uint4 v[5];
    if (p0 + 4 <= n) {
#pragma unroll
        for (int l = 0; l < 5; ++l)
            v[l] = *(const uint4*)(wsh + (size_t)(l + 3) * n + p0);
    } else {
#pragma unroll
        for (int l = 0; l < 5; ++l) {
            uint4 t;
            t.x = wsh[(size_t)(l+3)*n + min(p0+0, n-1)];
            t.y = wsh[(size_t)(l+3)*n + min(p0+1, n-1)];
            t.z = wsh[(size_t)(l+3)*n + min(p0+2, n-1)];
            t.w = wsh[(size_t)(l+3)*n + min(p0+3, n-1)];
            v[l] = t;
        }
    }

    // L0 (17), L1 (21), L2 (26) from fp16 LDS (scaled; unscale at write)
    float la[3][4], lb[3][4];
#pragma unroll
    for (int k = 0; k < 4; ++k) {
#pragma unroll
        for (int lv = 0; lv < 3; ++lv) {
            const float R  = (lv == 0) ? 16.f : (lv == 1) ? 20.f : 25.f;
            const int DIM  = (lv == 0) ? 17 : (lv == 1) ? 21 : 26;
            const int off  = (lv == 0) ? 0 : (lv == 1) ? DENSE_L1_OFF : DENSE_L2_OFF;
            const float g = 1.0f / R;
            const int D2 = DIM * DIM;
            const int bmax = DIM - 2;
            const float cx = fminf(fmaxf(px[k], 0.0f), 1.0f);
            const float cy = fminf(fmaxf(py[k], 0.0f), 1.0f);
            const float cz = fminf(fmaxf(pz[k], 0.0f), 1.0f);
            const int bx = min((int)floorf(cx * R), bmax);
            const int by = min((int)floorf(cy * R), bmax);
            const int bz = min((int)floorf(cz * R), bmax);
            const float wx = (px[k] - (float)bx * g) * R;
            const float wy = (py[k] - (float)by * g) * R;
            const float wz = (pz[k] - (float)bz * g) * R;
            const int c = off + (bx * DIM + by) * DIM + bz;
            const float2 e000 = h2f(lds[c]);
            const float2 e001 = h2f(lds[c + 1]);
            const float2 e010 = h2f(lds[c + DIM]);
            const float2 e011 = h2f(lds[c + DIM + 1]);
            const float2 e100 = h2f(lds[c + D2]);
            const float2 e101 = h2f(lds[c + D2 + 1]);
            const float2 e110 = h2f(lds[c + D2 + DIM]);
            const float2 e111 = h2f(lds[c + D2 + DIM + 1]);
            const float omx = 1.0f - wx, omy = 1.0f - wy, omz = 1.0f - wz;
            const float c00a = e000.x*omx + e100.x*wx, c00b = e000.y*omx + e100.y*wx;
            const float c01a = e001.x*omx + e101.x*wx, c01b = e001.y*omx + e101.y*wx;
            const float c10a = e010.x*omx + e110.x*wx, c10b = e010.y*omx + e110.y*wx;
            const float c11a = e011.x*omx + e111.x*wx, c11b = e011.y*omx + e111.y*wx;
            const float c0a = c00a*omy + c10a*wy, c0b = c00b*omy + c10b*wy;
            const float c1a = c01a*omy + c11a*wy, c1b = c01b*omy + c11b*wy;
            la[lv][k] = c0a*omz + c1a*wz;
            lb[lv][k] = c0b*omz + c1b*wz;
        }
    }

    // write AoS output
#pragma unroll
    for (int k = 0; k < 4; ++k) {
        if (p0 + k >= n) break;
        const float2 f3v = h2f(getc(v[0], k)), f4v = h2f(getc(v[1], k));
        const float2 f5v = h2f(getc(v[2], k)), f6v = h2f(getc(v[3], k));
        const float2 f7v = h2f(getc(v[4], k));
        float4* __restrict__ op = (float4*)(out + (size_t)(p0 + k) * 16);
        op[0] = make_float4(la[0][k]*FINV, lb[0][k]*FINV, la[1][k]*FINV, lb[1][k]*FINV);
        op[1] = make_float4(la[2][k]*FINV, lb[2][k]*FINV, f3v.x*FINV, f3v.y*FINV);
        op[2] = make_float4(f4v.x*FINV, f4v.y*FINV, f5v.x*FINV, f5v.y*FINV);
        op[3] = make_float4(f6v.x*FINV, f6v.y*FINV, f7v.x*FINV, f7v.y*FINV);
    }
}

// ---------------- fallback: monolithic, f32 exact -------------------------
__global__ __launch_bounds__(256) void hash_embed_mono_kernel(
    const float* __restrict__ x, const float* __restrict__ tables,
    float* __restrict__ out, int n)
{
    const int i = blockIdx.x * 256 + threadIdx.x;
    if (i >= n) return;
    const float px = x[3*i+0], py = x[3*i+1], pz = x[3*i+2];
    const float cx = fminf(fmaxf(px, 0.0f), 1.0f);
    const float cy = fminf(fmaxf(py, 0.0f), 1.0f);
    const float cz = fminf(fmaxf(pz, 0.0f), 1.0f);
    const float resf[8] = {16.f,20.f,25.f,32.f,40.f,50.f,64.f,80.f};
    float o[16];
#pragma unroll
    for (int l = 0; l < 8; ++l) {
        const float R = resf[l], g = 1.0f / R;
        const int bx = (int)floorf(cx*R), by = (int)floorf(cy*R), bz = (int)floorf(cz*R);
        const float wx = (px - bx*g)*R, wy = (py - by*g)*R, wz = (pz - bz*g)*R;
        const uint32_t hx0 = (uint32_t)bx, hx1 = hx0+1u;
        const uint32_t hy0 = (uint32_t)by*P2, hy1 = hy0+P2;
        const uint32_t hz0 = (uint32_t)bz*P3, hz1 = hz0+P3;
        const float2* tab = (const float2*)(tables) + (size_t)l*(size_t)TABLE_SIZE;
        const float2 e000 = tab[(hx0^hy0^hz0)&TMASK], e001 = tab[(hx0^hy0^hz1)&TMASK];
        const float2 e010 = tab[(hx0^hy1^hz0)&TMASK], e011 = tab[(hx0^hy1^hz1)&TMASK];
        const float2 e100 = tab[(hx1^hy0^hz0)&TMASK], e101 = tab[(hx1^hy0^hz1)&TMASK];
        const float2 e110 = tab[(hx1^hy1^hz0)&TMASK], e111 = tab[(hx1^hy1^hz1)&TMASK];
        const float omx = 1.f-wx, omy = 1.f-wy, omz = 1.f-wz;
        const float c00a = e000.x*omx + e100.x*wx, c00b = e000.y*omx + e100.y*wx;
        const float c01a = e001.x*omx + e101.x*wx, c01b = e001.y*omx + e101.y*wx;
        const float c10a = e010.x*omx + e110.x*wx, c10b = e010.y*omx + e110.y*wx;
        const float c11a = e011.x*omx + e111.x*wx, c11b = e011.y*omx + e111.y*wx;
        const float c0a = c00a*omy + c10a*wy, c0b = c00b*omy + c10b*wy;
        const float c1a = c01a*omy + c11a*wy, c1b = c01b*omy + c11b*wy;
        o[2*l+0] = c0a*omz + c1a*wz;
        o[2*l+1] = c0b*omz + c1b*wz;
    }
    float4* op = (float4*)(out + (size_t)i * 16);
    op[0] = make_float4(o[0],o[1],o[2],o[3]);
    op[1] = make_float4(o[4],o[5],o[6],o[7]);
    op[2] = make_float4(o[8],o[9],o[10],o[11]);
    op[3] = make_float4(o[12],o[13],o[14],o[15]);
}

extern "C" void kernel_launch(void* const* d_in, const int* in_sizes, int n_in,
                              void* d_out, int out_size, void* d_ws, size_t ws_size,
                              hipStream_t stream) {
    const float* x = (const float*)d_in[0];
    const float* tables = (const float*)d_in[1];
    float* out = (float*)d_out;
    const int n = in_sizes[0] / 3;  // 1048576 points

    // 127KB dynamic LDS needs opt-in; wsh needs 8*n*4B = 32MB.
    static int cap = -1;
    if (cap < 0) {
        cap = (hipFuncSetAttribute((const void*)final_kernel,
                  hipFuncAttributeMaxDynamicSharedMemorySize, DENSE_BYTES) == hipSuccess)
              ? 1 : 0;
    }
    const size_t ws_needed = (size_t)8 * (size_t)n * sizeof(uint32_t);  // 32 MB
    if (ws_size < ws_needed || cap == 0) {
        hash_embed_mono_kernel<<<(n + 255) / 256, 256, 0, stream>>>(x, tables, out, n);
        return;
    }

    uint32_t* wsh = (uint32_t*)d_ws;            // rows 3..7 used by embed
    uint32_t* dense = (uint32_t*)d_ws;          // dense fp16 in row-0 head (127KB)
    uint4*  quads = (uint4*)((char*)out + QUAD_BYTES_OFF);
    uint2*  pairs = (uint2*)((char*)out + PAIR_BYTES_OFF);

    // k0: all derived tables, one launch (grid.y: 4 quad levels, pair7, dense)
    build_tables_kernel<<<dim3(2051, 6), 256, 0, stream>>>(tables, dense, quads, pairs);

    // k1: per-group gather: {3,4} paired, {5}, {6}, {7}; group-major order
    const int bpl = (n + 1023) / 1024;
    embed_levels_kernel<<<4 * bpl, 256, 0, stream>>>(x, quads, pairs, wsh, n, bpl);

    // k2: fused final (L0+L1+L2 fp16 LDS + unpack rows 3..7 -> AoS out)
    final_kernel<<<(n + 4095) / 4096, 1024, DENSE_BYTES, stream>>>(x, wsh, out, n);
}